// Round 3
// baseline (443.109 us; speedup 1.0000x reference)
//
#include <hip/hip_runtime.h>
#include <math.h>

#define NB 8
#define NS 2048
#define ND 512
#define NHH 8
#define NDH 64

typedef __attribute__((ext_vector_type(4))) float f32x4;
typedef __attribute__((ext_vector_type(8))) short bf16x8;
typedef unsigned short ush;

__device__ inline ush f2bf_rne(float f) {
    unsigned u = __float_as_uint(f);
    unsigned r = u + 0x7FFFu + ((u >> 16) & 1u);
    return (ush)(r >> 16);
}
__device__ inline float bf2f(ush h) { return __uint_as_float(((unsigned)h) << 16); }

// packed f32x2 -> bf16x2 (RNE), single VALU instruction
__device__ inline unsigned cvt_pk_bf16(float lo, float hi) {
    unsigned r;
    asm("v_cvt_pk_bf16_f32 %0, %1, %2" : "=v"(r) : "v"(lo), "v"(hi));
    return r;
}

#if defined(__has_builtin)
#if __has_builtin(__builtin_amdgcn_exp2f)
#define EXP2F(x) __builtin_amdgcn_exp2f(x)
#else
#define EXP2F(x) exp2f(x)
#endif
#else
#define EXP2F(x) exp2f(x)
#endif

// async global->LDS, 16B per lane (global_load_lds_dwordx4)
#define GLL16(gp, lp) __builtin_amdgcn_global_load_lds( \
    (const __attribute__((address_space(1))) unsigned int*)(gp), \
    (__attribute__((address_space(3))) unsigned int*)(lp), 16, 0, 0)

// ---------------------------------------------------------------------------
// Kernel 0: weight conversion. y<3: Wq/Wk/Wv -> bf16. y==3: Wo -> hi/lo bf16.
// ---------------------------------------------------------------------------
__global__ __launch_bounds__(256) void conv_w_kernel(
    const float* __restrict__ Wq, const float* __restrict__ Wk,
    const float* __restrict__ Wv, const float* __restrict__ Wo,
    ush* __restrict__ wbf, ush* __restrict__ wo_hi, ush* __restrict__ wo_lo)
{
    const int y = blockIdx.y;
    const int i = (blockIdx.x * 256 + threadIdx.x) * 4;
    if (y < 3) {
        const float* src = (y == 0) ? Wq : (y == 1) ? Wk : Wv;
        const float4 v = *(const float4*)&src[i];
        ushort4 o;
        o.x = f2bf_rne(v.x); o.y = f2bf_rne(v.y);
        o.z = f2bf_rne(v.z); o.w = f2bf_rne(v.w);
        *(ushort4*)&wbf[y * 262144 + i] = o;
    } else {
        const float4 v = *(const float4*)&Wo[i];
        ushort4 hi, lo;
        hi.x = f2bf_rne(v.x); lo.x = f2bf_rne(v.x - bf2f(hi.x));
        hi.y = f2bf_rne(v.y); lo.y = f2bf_rne(v.y - bf2f(hi.y));
        hi.z = f2bf_rne(v.z); lo.z = f2bf_rne(v.z - bf2f(hi.z));
        hi.w = f2bf_rne(v.w); lo.w = f2bf_rne(v.w - bf2f(hi.w));
        *(ushort4*)&wo_hi[i] = hi;
        *(ushort4*)&wo_lo[i] = lo;
    }
}

// ---------------------------------------------------------------------------
// Kernel 1: QKV projections via bf16 MFMA. C = X @ W^T + b.
// 128x128 tile, BK=32, 4 waves (2x2 of 64x64), 16x16x32 MFMA.
// LDS layout (per 16-row chunk): slot i (16B) holds row (i>>2), k-group
// g = (i&3) ^ s(i>>2), s(r) = (r + (r>>2)) & 3  -> staging writes and
// ds_read_b128 frag reads both hit the quarter-wave bank floor.
// A (x fp32) converted in-staging; B (weights bf16) staged via GLL16.
// Epilogue: z=0 Q (scaled 0.125*log2e, B,H,S,DH bf16); z=1 K (same, scale 1);
// z=2 V stored TRANSPOSED (B,H,DH,S) via packed ushort4 (r-consecutive rows).
// ---------------------------------------------------------------------------
__global__ __launch_bounds__(256) void qkv_gemm_kernel(
    const float* __restrict__ xq, const float* __restrict__ xk, const float* __restrict__ xv,
    const ush* __restrict__ wbf,
    const float* __restrict__ bq, const float* __restrict__ bk, const float* __restrict__ bv,
    ush* __restrict__ Qb, ush* __restrict__ Kb, ush* __restrict__ VT)
{
    __shared__ ush As[4096];   // 8 chunks x 512 shorts = 8 KB
    __shared__ ush Bs[4096];

    const int z = blockIdx.z;
    const float* X    = (z == 0) ? xq : (z == 1) ? xk : xv;
    const ush*   W    = wbf + z * 262144;
    const float* bias = (z == 0) ? bq : (z == 1) ? bk : bv;

    const int t = threadIdx.x;
    const int w = t >> 6, l = t & 63;
    const int l15 = l & 15, g = l >> 4;
    const int m0 = blockIdx.x * 128, n0 = blockIdx.y * 128;
    const int wm = (w & 1) << 6, wn = (w >> 1) << 6;

    const int srow = l >> 2;                                   // row within chunk
    const int sg   = (l & 3) ^ ((srow + (srow >> 2)) & 3);     // staged k-group
    const int fsw  = (g ^ ((l15 + (l15 >> 2)) & 3)) << 3;      // frag-read swizzle (shorts)
    const int c0   = w * 2;                                    // this wave's chunks

    f32x4 acc[4][4];
    #pragma unroll
    for (int i = 0; i < 4; ++i)
        #pragma unroll
        for (int j = 0; j < 4; ++j) acc[i][j] = (f32x4)(0.0f);

    for (int kt = 0; kt < 512; kt += 32) {
        // A source loads (fp32), before barrier (no LDS hazard)
        const size_t ar0 = (size_t)(m0 + c0 * 16 + srow) * 512 + kt + sg * 8;
        const size_t ar1 = (size_t)(m0 + (c0 + 1) * 16 + srow) * 512 + kt + sg * 8;
        const float4 a0 = *(const float4*)&X[ar0];
        const float4 a1 = *(const float4*)&X[ar0 + 4];
        const float4 a2 = *(const float4*)&X[ar1];
        const float4 a3 = *(const float4*)&X[ar1 + 4];

        __syncthreads();   // previous iteration's frag reads complete

        // B: async bf16 staging
        GLL16(&W[(size_t)(n0 + c0 * 16 + srow) * 512 + kt + sg * 8], &Bs[c0 * 512 + l * 8]);
        GLL16(&W[(size_t)(n0 + (c0 + 1) * 16 + srow) * 512 + kt + sg * 8], &Bs[(c0 + 1) * 512 + l * 8]);

        // A: convert + ds_write_b128
        uint4 u0, u1;
        u0.x = (unsigned)f2bf_rne(a0.x) | ((unsigned)f2bf_rne(a0.y) << 16);
        u0.y = (unsigned)f2bf_rne(a0.z) | ((unsigned)f2bf_rne(a0.w) << 16);
        u0.z = (unsigned)f2bf_rne(a1.x) | ((unsigned)f2bf_rne(a1.y) << 16);
        u0.w = (unsigned)f2bf_rne(a1.z) | ((unsigned)f2bf_rne(a1.w) << 16);
        u1.x = (unsigned)f2bf_rne(a2.x) | ((unsigned)f2bf_rne(a2.y) << 16);
        u1.y = (unsigned)f2bf_rne(a2.z) | ((unsigned)f2bf_rne(a2.w) << 16);
        u1.z = (unsigned)f2bf_rne(a3.x) | ((unsigned)f2bf_rne(a3.y) << 16);
        u1.w = (unsigned)f2bf_rne(a3.z) | ((unsigned)f2bf_rne(a3.w) << 16);
        *(uint4*)&As[c0 * 512 + l * 8] = u0;
        *(uint4*)&As[(c0 + 1) * 512 + l * 8] = u1;

        __syncthreads();   // staged tile visible (compiler drains vmcnt+lgkm)

        bf16x8 af[4], bfr[4];
        #pragma unroll
        for (int mi = 0; mi < 4; ++mi)
            af[mi] = *(const bf16x8*)&As[(((w & 1) << 2) + mi) * 512 + l15 * 32 + fsw];
        #pragma unroll
        for (int ni = 0; ni < 4; ++ni)
            bfr[ni] = *(const bf16x8*)&Bs[(((w >> 1) << 2) + ni) * 512 + l15 * 32 + fsw];
        #pragma unroll
        for (int mi = 0; mi < 4; ++mi)
            #pragma unroll
            for (int ni = 0; ni < 4; ++ni)
                acc[mi][ni] = __builtin_amdgcn_mfma_f32_16x16x32_bf16(af[mi], bfr[ni], acc[mi][ni], 0, 0, 0);
    }

    const float qscale = (z == 0) ? 0.18033688011112042f : 1.0f;   // 0.125*log2(e)
    float bnv[4];
    #pragma unroll
    for (int ni = 0; ni < 4; ++ni) bnv[ni] = bias[n0 + wn + ni * 16 + l15];

    if (z < 2) {
        ush* O = (z == 0) ? Qb : Kb;
        #pragma unroll
        for (int mi = 0; mi < 4; ++mi) {
            #pragma unroll
            for (int ni = 0; ni < 4; ++ni) {
                const int n = n0 + wn + ni * 16 + l15;
                const int hh = n >> 6, dh = n & 63;
                #pragma unroll
                for (int r = 0; r < 4; ++r) {
                    const int m = m0 + wm + mi * 16 + (g << 2) + r;
                    const int bi = m >> 11, s = m & (NS - 1);
                    O[((size_t)(bi * 8 + hh) * 2048 + s) * 64 + dh] =
                        f2bf_rne((acc[mi][ni][r] + bnv[ni]) * qscale);
                }
            }
        }
    } else {
        #pragma unroll
        for (int mi = 0; mi < 4; ++mi) {
            #pragma unroll
            for (int ni = 0; ni < 4; ++ni) {
                const int n = n0 + wn + ni * 16 + l15;
                const int hh = n >> 6, dh = n & 63;
                const int mb = m0 + wm + mi * 16 + (g << 2);
                const int bi = mb >> 11, s = mb & (NS - 1);
                ushort4 pk;
                pk.x = f2bf_rne(acc[mi][ni][0] + bnv[ni]);
                pk.y = f2bf_rne(acc[mi][ni][1] + bnv[ni]);
                pk.z = f2bf_rne(acc[mi][ni][2] + bnv[ni]);
                pk.w = f2bf_rne(acc[mi][ni][3] + bnv[ni]);
                *(ushort4*)&VT[((size_t)(bi * 8 + hh) * 64 + dh) * 2048 + s] = pk;
            }
        }
    }
}

// ---------------------------------------------------------------------------
// Kernel 2: flash attention, S^T formulation — BARRIER-FREE.
// S^T = K·Q^T (A=K-frag, B=Q-frag). P^T packed via v_cvt_pk_bf16_f32 in
// registers; Ps is WAVE-PRIVATE (wave w owns rows w*16..w*16+15, writes and
// reads only those) so no __syncthreads is ever needed. V B-fragments are
// loaded DIRECTLY from global VT (B,H,DH,S): addresses are identical across
// the block's 4 waves (L1 serves 3/4) and shared by the 32 blocks on the
// same (b,h) (L2-resident, 256 KB/head). Denominator l via MFMA against a
// ones-fragment (sums the same rounded-bf16 P as the numerator). Key loop
// split: full tiles carry no masking code; one boundary tile does cndmask.
// s_setprio(1) wraps the MFMA clusters (independent-wave regime).
// ctx written as bf16 hi/lo; hi overwrites Qb in place.
// ---------------------------------------------------------------------------
__global__ __launch_bounds__(256) void attn_kernel(
    ush* __restrict__ Qb, const ush* __restrict__ Kb,
    const ush* __restrict__ VT, const int* __restrict__ lens,
    ush* __restrict__ ctx_lo)
{
    __shared__ ush Ps[64 * 72];   // [q_local][key], stride 72, wave-private rows

    const int tid = threadIdx.x;
    const int w = tid >> 6, l = tid & 63;
    const int l15 = l & 15, g = l >> 4;

    const int id = blockIdx.x;
    const int h = id & 7, qt = (id >> 3) & 31, b = id >> 8;
    const int L = lens[b];
    const int q0 = qt << 6;
    const size_t bh = ((size_t)b * 8 + h) * 2048;

    // Q B-fragments (held all kernel)
    const ush* qptr = Qb + (bh + q0 + w * 16 + l15) * 64 + g * 8;
    const bf16x8 qf0 = *(const bf16x8*)(qptr);
    const bf16x8 qf1 = *(const bf16x8*)(qptr + 32);

    const ush* kbase = Kb + (bh + l15) * 64 + g * 8;
    // V fragment base: VT row (dv = st2*16 + l15), key col g*8 (+ k0 per tile)
    // VT head slice starts at (b*8+h)*64*2048 == bh*64
    const ush* vfbase = VT + bh * 64 + (size_t)l15 * 2048 + g * 8;

    // Ps pointers (this thread; wave-private rows)
    ush* psw = &Ps[(w * 16 + l15) * 72 + (g << 2)];        // P^T write slot
    const ush* pp = &Ps[(w * 16 + l15) * 72 + g * 8];      // A-frag read slot

    // constant ones B-fragment for the l-MFMA (bf16 1.0 = 0x3F80)
    bf16x8 ones;
    #pragma unroll
    for (int j = 0; j < 8; ++j) ones[j] = (short)0x3F80;

    f32x4 o[4];
    f32x4 ol = (f32x4)(0.0f);   // ol[r] = sum_k P[q=g*4+r][k]
    #pragma unroll
    for (int i = 0; i < 4; ++i) o[i] = (f32x4)(0.0f);

    auto tile = [&](int k0, bool masked) {
        // V first half (keys k0..k0+31): issue before anything else
        const ush* vp = vfbase + k0;
        bf16x8 vfA[4], vfB[4];
        #pragma unroll
        for (int st2 = 0; st2 < 4; ++st2)
            vfA[st2] = *(const bf16x8*)(vp + st2 * 16 * 2048);

        // K loads + S^T MFMA
        f32x4 s[4];
        #pragma unroll
        for (int st = 0; st < 4; ++st) s[st] = (f32x4)(0.0f);
        const ush* kp = kbase + (size_t)k0 * 64;
        __builtin_amdgcn_s_setprio(1);
        #pragma unroll
        for (int st = 0; st < 4; ++st) {
            const bf16x8 kf0 = *(const bf16x8*)(kp + st * 16 * 64);
            const bf16x8 kf1 = *(const bf16x8*)(kp + st * 16 * 64 + 32);
            s[st] = __builtin_amdgcn_mfma_f32_16x16x32_bf16(kf0, qf0, s[st], 0, 0, 0);
            s[st] = __builtin_amdgcn_mfma_f32_16x16x32_bf16(kf1, qf1, s[st], 0, 0, 0);
        }
        __builtin_amdgcn_s_setprio(0);

        // V second half (keys k0+32..k0+63): issue under the S-MFMA shadow
        #pragma unroll
        for (int st2 = 0; st2 < 4; ++st2)
            vfB[st2] = *(const bf16x8*)(vp + st2 * 16 * 2048 + 32);

        // no-max softmax, fully in registers
        uint2 pk[4];
        #pragma unroll
        for (int st = 0; st < 4; ++st) {
            float p[4];
            #pragma unroll
            for (int r = 0; r < 4; ++r) {
                float e = EXP2F(s[st][r]);
                if (masked) {
                    const int key = k0 + st * 16 + (g << 2) + r;
                    e = (key < L) ? e : 0.0f;
                }
                p[r] = e;
            }
            pk[st].x = cvt_pk_bf16(p[0], p[1]);
            pk[st].y = cvt_pk_bf16(p[2], p[3]);
        }

        // wave-private Ps round-trip (lgkmcnt-ordered, no barrier)
        #pragma unroll
        for (int st = 0; st < 4; ++st)
            *(uint2*)(psw + st * 16) = pk[st];
        const bf16x8 pf0 = *(const bf16x8*)(pp);
        const bf16x8 pf1 = *(const bf16x8*)(pp + 32);

        // O += P @ V ; l += P @ ones
        __builtin_amdgcn_s_setprio(1);
        ol = __builtin_amdgcn_mfma_f32_16x16x32_bf16(pf0, ones, ol, 0, 0, 0);
        #pragma unroll
        for (int st2 = 0; st2 < 4; ++st2)
            o[st2] = __builtin_amdgcn_mfma_f32_16x16x32_bf16(pf0, vfA[st2], o[st2], 0, 0, 0);
        ol = __builtin_amdgcn_mfma_f32_16x16x32_bf16(pf1, ones, ol, 0, 0, 0);
        #pragma unroll
        for (int st2 = 0; st2 < 4; ++st2)
            o[st2] = __builtin_amdgcn_mfma_f32_16x16x32_bf16(pf1, vfB[st2], o[st2], 0, 0, 0);
        __builtin_amdgcn_s_setprio(0);
    };

    const int nfull = L >> 6;
    for (int kt = 0; kt < nfull; ++kt) tile(kt << 6, false);
    if (L & 63) tile(nfull << 6, true);

    #pragma unroll
    for (int r = 0; r < 4; ++r) {
        const float inv = 1.0f / ol[r];   // l for q = g*4+r, lane-local
        const size_t row = bh + q0 + w * 16 + (g << 2) + r;
        #pragma unroll
        for (int st2 = 0; st2 < 4; ++st2) {
            const float val = o[st2][r] * inv;
            const ush hi = f2bf_rne(val);
            const ush lo = f2bf_rne(val - bf2f(hi));
            Qb[row * 64 + st2 * 16 + l15] = hi;        // ctx_hi in place
            ctx_lo[row * 64 + st2 * 16 + l15] = lo;
        }
    }
}

// ---------------------------------------------------------------------------
// Kernel 3: out = ctx @ Wo^T + bo, 3-term split bf16 MFMA
// (hi·hi + lo·hi + hi·lo ~ fp32 accuracy). ctx gathered from (B,H,S,DH).
// ---------------------------------------------------------------------------
__global__ __launch_bounds__(256) void out_gemm_kernel(
    const ush* __restrict__ ctx_hi, const ush* __restrict__ ctx_lo,
    const ush* __restrict__ wo_hi, const ush* __restrict__ wo_lo,
    const float* __restrict__ bo, float* __restrict__ out)
{
    __shared__ ush Ah[4096], Al[4096], Bh[4096], Bl[4096];

    const int t = threadIdx.x;
    const int w = t >> 6, l = t & 63;
    const int l15 = l & 15, g = l >> 4;
    const int m0 = blockIdx.x * 128, n0 = blockIdx.y * 128;
    const int wm = (w & 1) << 6, wn = (w >> 1) << 6;

    const int srow = l >> 2;
    const int sg   = (l & 3) ^ ((srow + (srow >> 2)) & 3);
    const int fsw  = (g ^ ((l15 + (l15 >> 2)) & 3)) << 3;
    const int c0   = w * 2;

    f32x4 acc[4][4];
    #pragma unroll
    for (int i = 0; i < 4; ++i)
        #pragma unroll
        for (int j = 0; j < 4; ++j) acc[i][j] = (f32x4)(0.0f);

    for (int kt = 0; kt < 512; kt += 32) {
        __syncthreads();   // previous frag reads complete
        #pragma unroll
        for (int cc = 0; cc < 2; ++cc) {
            const int c = c0 + cc;
            // ctx rows: token m; k = h*64 + dh (BK=32 stays inside one head)
            const int m = m0 + c * 16 + srow;
            const int k = kt + sg * 8;
            const size_t ga = ((size_t)((m >> 11) * 8 + (k >> 6)) * 2048 + (m & (NS - 1))) * 64 + (k & 63);
            GLL16(&ctx_hi[ga], &Ah[c * 512 + l * 8]);
            GLL16(&ctx_lo[ga], &Al[c * 512 + l * 8]);
            const size_t gb = (size_t)(n0 + c * 16 + srow) * 512 + kt + sg * 8;
            GLL16(&wo_hi[gb], &Bh[c * 512 + l * 8]);
            GLL16(&wo_lo[gb], &Bl[c * 512 + l * 8]);
        }
        __syncthreads();   // staged

        bf16x8 ah[4], al[4], bh4[4], bl4[4];
        #pragma unroll
        for (int mi = 0; mi < 4; ++mi) {
            const int off = (((w & 1) << 2) + mi) * 512 + l15 * 32 + fsw;
            ah[mi] = *(const bf16x8*)&Ah[off];
            al[mi] = *(const bf16x8*)&Al[off];
        }
        #pragma unroll
        for (int ni = 0; ni < 4; ++ni) {
            const int off = (((w >> 1) << 2) + ni) * 512 + l15 * 32 + fsw;
            bh4[ni] = *(const bf16x8*)&Bh[off];
            bl4[ni] = *(const bf16x8*)&Bl[off];
        }
        #pragma unroll
        for (int mi = 0; mi < 4; ++mi)
            #pragma unroll
            for (int ni = 0; ni < 4; ++ni) {
                acc[mi][ni] = __builtin_amdgcn_mfma_f32_16x16x32_bf16(ah[mi], bh4[ni], acc[mi][ni], 0, 0, 0);
                acc[mi][ni] = __builtin_amdgcn_mfma_f32_16x16x32_bf16(al[mi], bh4[ni], acc[mi][ni], 0, 0, 0);
                acc[mi][ni] = __builtin_amdgcn_mfma_f32_16x16x32_bf16(ah[mi], bl4[ni], acc[mi][ni], 0, 0, 0);
            }
    }

    float bov[4];
    #pragma unroll
    for (int ni = 0; ni < 4; ++ni) bov[ni] = bo[n0 + wn + ni * 16 + l15];

    #pragma unroll
    for (int mi = 0; mi < 4; ++mi)
        #pragma unroll
        for (int ni = 0; ni < 4; ++ni) {
            const int n = n0 + wn + ni * 16 + l15;
            #pragma unroll
            for (int r = 0; r < 4; ++r) {
                const int m = m0 + wm + mi * 16 + (g << 2) + r;
                out[(size_t)m * 512 + n] = acc[mi][ni][r] + bov[ni];
            }
        }
}

// ---------------------------------------------------------------------------
extern "C" void kernel_launch(void* const* d_in, const int* in_sizes, int n_in,
                              void* d_out, int out_size, void* d_ws, size_t ws_size,
                              hipStream_t stream)
{
    const float* xq   = (const float*)d_in[0];
    const float* xk   = (const float*)d_in[1];
    const float* xv   = (const float*)d_in[2];
    const float* Wq   = (const float*)d_in[3];
    const float* bq   = (const float*)d_in[4];
    const float* Wk   = (const float*)d_in[5];
    const float* bk   = (const float*)d_in[6];
    const float* Wv   = (const float*)d_in[7];
    const float* bv   = (const float*)d_in[8];
    const float* Wo   = (const float*)d_in[9];
    const float* bo   = (const float*)d_in[10];
    const int*   lens = (const int*)d_in[11];
    float* out = (float*)d_out;

    const size_t elems = (size_t)NB * NHH * NS * NDH;   // 8.39M
    ush* Qb     = (ush*)d_ws;          // bf16 Q (pre-scaled); later ctx_hi in place
    ush* Kb     = Qb + elems;
    ush* VT     = Kb + elems;          // V transposed (B,H,DH,S)
    ush* ctx_lo = VT + elems;
    ush* wbf    = ctx_lo + elems;      // Wq,Wk,Wv bf16 (3*262144)
    ush* wo_hi  = wbf + 3 * 262144;
    ush* wo_lo  = wo_hi + 262144;
    // total: 4*8.39M + 5*262144 shorts = 69.7 MB (< 100.7 MB proven in R1)

    const dim3 blk(256);
    conv_w_kernel<<<dim3(256, 4), blk, 0, stream>>>(Wq, Wk, Wv, Wo, wbf, wo_hi, wo_lo);
    qkv_gemm_kernel<<<dim3(128, 4, 3), blk, 0, stream>>>(
        xq, xk, xv, wbf, bq, bk, bv, Qb, Kb, VT);
    attn_kernel<<<dim3(NB * NHH * (NS / 64)), blk, 0, stream>>>(Qb, Kb, VT, lens, ctx_lo);
    out_gemm_kernel<<<dim3(128, 4), blk, 0, stream>>>(Qb, ctx_lo, wo_hi, wo_lo, bo, out);
}

// Round 4
// 354.850 us; speedup vs baseline: 1.2487x; 1.2487x over previous
//
#include <hip/hip_runtime.h>
#include <math.h>

#define NB 8
#define NS 2048
#define ND 512
#define NHH 8
#define NDH 64

typedef __attribute__((ext_vector_type(4))) float f32x4;
typedef __attribute__((ext_vector_type(8))) short bf16x8;
typedef unsigned short ush;

__device__ inline ush f2bf_rne(float f) {
    unsigned u = __float_as_uint(f);
    unsigned r = u + 0x7FFFu + ((u >> 16) & 1u);
    return (ush)(r >> 16);
}
__device__ inline float bf2f(ush h) { return __uint_as_float(((unsigned)h) << 16); }

// packed f32x2 -> bf16x2 (RNE), single VALU instruction
__device__ inline unsigned cvt_pk_bf16(float lo, float hi) {
    unsigned r;
    asm("v_cvt_pk_bf16_f32 %0, %1, %2" : "=v"(r) : "v"(lo), "v"(hi));
    return r;
}

#if defined(__has_builtin)
#if __has_builtin(__builtin_amdgcn_exp2f)
#define EXP2F(x) __builtin_amdgcn_exp2f(x)
#else
#define EXP2F(x) exp2f(x)
#endif
#else
#define EXP2F(x) exp2f(x)
#endif

// async global->LDS, 16B per lane (global_load_lds_dwordx4)
#define GLL16(gp, lp) __builtin_amdgcn_global_load_lds( \
    (const __attribute__((address_space(1))) unsigned int*)(gp), \
    (__attribute__((address_space(3))) unsigned int*)(lp), 16, 0, 0)

// ---------------------------------------------------------------------------
// Kernel 0: weight conversion. y<3: Wq/Wk/Wv -> bf16. y==3: Wo -> hi/lo bf16.
// ---------------------------------------------------------------------------
__global__ __launch_bounds__(256) void conv_w_kernel(
    const float* __restrict__ Wq, const float* __restrict__ Wk,
    const float* __restrict__ Wv, const float* __restrict__ Wo,
    ush* __restrict__ wbf, ush* __restrict__ wo_hi, ush* __restrict__ wo_lo)
{
    const int y = blockIdx.y;
    const int i = (blockIdx.x * 256 + threadIdx.x) * 4;
    if (y < 3) {
        const float* src = (y == 0) ? Wq : (y == 1) ? Wk : Wv;
        const float4 v = *(const float4*)&src[i];
        ushort4 o;
        o.x = f2bf_rne(v.x); o.y = f2bf_rne(v.y);
        o.z = f2bf_rne(v.z); o.w = f2bf_rne(v.w);
        *(ushort4*)&wbf[y * 262144 + i] = o;
    } else {
        const float4 v = *(const float4*)&Wo[i];
        ushort4 hi, lo;
        hi.x = f2bf_rne(v.x); lo.x = f2bf_rne(v.x - bf2f(hi.x));
        hi.y = f2bf_rne(v.y); lo.y = f2bf_rne(v.y - bf2f(hi.y));
        hi.z = f2bf_rne(v.z); lo.z = f2bf_rne(v.z - bf2f(hi.z));
        hi.w = f2bf_rne(v.w); lo.w = f2bf_rne(v.w - bf2f(hi.w));
        *(ushort4*)&wo_hi[i] = hi;
        *(ushort4*)&wo_lo[i] = lo;
    }
}

// ---------------------------------------------------------------------------
// Kernel 1: QKV projections via bf16 MFMA. C = X @ W^T + b.
// 128x128 tile, BK=32, 4 waves (2x2 of 64x64), 16x16x32 MFMA.
// LDS layout (per 16-row chunk): slot i (16B) holds row (i>>2), k-group
// g = (i&3) ^ s(i>>2), s(r) = (r + (r>>2)) & 3  -> staging writes and
// ds_read_b128 frag reads both hit the quarter-wave bank floor.
// A (x fp32) converted in-staging; B (weights bf16) staged via GLL16.
// Epilogue: z=0 Q (scaled 0.125*log2e, B,H,S,DH bf16); z=1 K (same, scale 1);
// z=2 V stored TRANSPOSED (B,H,DH,S) via packed ushort4 (r-consecutive rows).
// ---------------------------------------------------------------------------
__global__ __launch_bounds__(256) void qkv_gemm_kernel(
    const float* __restrict__ xq, const float* __restrict__ xk, const float* __restrict__ xv,
    const ush* __restrict__ wbf,
    const float* __restrict__ bq, const float* __restrict__ bk, const float* __restrict__ bv,
    ush* __restrict__ Qb, ush* __restrict__ Kb, ush* __restrict__ VT)
{
    __shared__ ush As[4096];   // 8 chunks x 512 shorts = 8 KB
    __shared__ ush Bs[4096];

    const int z = blockIdx.z;
    const float* X    = (z == 0) ? xq : (z == 1) ? xk : xv;
    const ush*   W    = wbf + z * 262144;
    const float* bias = (z == 0) ? bq : (z == 1) ? bk : bv;

    const int t = threadIdx.x;
    const int w = t >> 6, l = t & 63;
    const int l15 = l & 15, g = l >> 4;
    const int m0 = blockIdx.x * 128, n0 = blockIdx.y * 128;
    const int wm = (w & 1) << 6, wn = (w >> 1) << 6;

    const int srow = l >> 2;                                   // row within chunk
    const int sg   = (l & 3) ^ ((srow + (srow >> 2)) & 3);     // staged k-group
    const int fsw  = (g ^ ((l15 + (l15 >> 2)) & 3)) << 3;      // frag-read swizzle (shorts)
    const int c0   = w * 2;                                    // this wave's chunks

    f32x4 acc[4][4];
    #pragma unroll
    for (int i = 0; i < 4; ++i)
        #pragma unroll
        for (int j = 0; j < 4; ++j) acc[i][j] = (f32x4)(0.0f);

    for (int kt = 0; kt < 512; kt += 32) {
        // A source loads (fp32), before barrier (no LDS hazard)
        const size_t ar0 = (size_t)(m0 + c0 * 16 + srow) * 512 + kt + sg * 8;
        const size_t ar1 = (size_t)(m0 + (c0 + 1) * 16 + srow) * 512 + kt + sg * 8;
        const float4 a0 = *(const float4*)&X[ar0];
        const float4 a1 = *(const float4*)&X[ar0 + 4];
        const float4 a2 = *(const float4*)&X[ar1];
        const float4 a3 = *(const float4*)&X[ar1 + 4];

        __syncthreads();   // previous iteration's frag reads complete

        // B: async bf16 staging
        GLL16(&W[(size_t)(n0 + c0 * 16 + srow) * 512 + kt + sg * 8], &Bs[c0 * 512 + l * 8]);
        GLL16(&W[(size_t)(n0 + (c0 + 1) * 16 + srow) * 512 + kt + sg * 8], &Bs[(c0 + 1) * 512 + l * 8]);

        // A: convert + ds_write_b128
        uint4 u0, u1;
        u0.x = (unsigned)f2bf_rne(a0.x) | ((unsigned)f2bf_rne(a0.y) << 16);
        u0.y = (unsigned)f2bf_rne(a0.z) | ((unsigned)f2bf_rne(a0.w) << 16);
        u0.z = (unsigned)f2bf_rne(a1.x) | ((unsigned)f2bf_rne(a1.y) << 16);
        u0.w = (unsigned)f2bf_rne(a1.z) | ((unsigned)f2bf_rne(a1.w) << 16);
        u1.x = (unsigned)f2bf_rne(a2.x) | ((unsigned)f2bf_rne(a2.y) << 16);
        u1.y = (unsigned)f2bf_rne(a2.z) | ((unsigned)f2bf_rne(a2.w) << 16);
        u1.z = (unsigned)f2bf_rne(a3.x) | ((unsigned)f2bf_rne(a3.y) << 16);
        u1.w = (unsigned)f2bf_rne(a3.z) | ((unsigned)f2bf_rne(a3.w) << 16);
        *(uint4*)&As[c0 * 512 + l * 8] = u0;
        *(uint4*)&As[(c0 + 1) * 512 + l * 8] = u1;

        __syncthreads();   // staged tile visible (compiler drains vmcnt+lgkm)

        bf16x8 af[4], bfr[4];
        #pragma unroll
        for (int mi = 0; mi < 4; ++mi)
            af[mi] = *(const bf16x8*)&As[(((w & 1) << 2) + mi) * 512 + l15 * 32 + fsw];
        #pragma unroll
        for (int ni = 0; ni < 4; ++ni)
            bfr[ni] = *(const bf16x8*)&Bs[(((w >> 1) << 2) + ni) * 512 + l15 * 32 + fsw];
        #pragma unroll
        for (int mi = 0; mi < 4; ++mi)
            #pragma unroll
            for (int ni = 0; ni < 4; ++ni)
                acc[mi][ni] = __builtin_amdgcn_mfma_f32_16x16x32_bf16(af[mi], bfr[ni], acc[mi][ni], 0, 0, 0);
    }

    const float qscale = (z == 0) ? 0.18033688011112042f : 1.0f;   // 0.125*log2(e)
    float bnv[4];
    #pragma unroll
    for (int ni = 0; ni < 4; ++ni) bnv[ni] = bias[n0 + wn + ni * 16 + l15];

    if (z < 2) {
        ush* O = (z == 0) ? Qb : Kb;
        #pragma unroll
        for (int mi = 0; mi < 4; ++mi) {
            #pragma unroll
            for (int ni = 0; ni < 4; ++ni) {
                const int n = n0 + wn + ni * 16 + l15;
                const int hh = n >> 6, dh = n & 63;
                #pragma unroll
                for (int r = 0; r < 4; ++r) {
                    const int m = m0 + wm + mi * 16 + (g << 2) + r;
                    const int bi = m >> 11, s = m & (NS - 1);
                    O[((size_t)(bi * 8 + hh) * 2048 + s) * 64 + dh] =
                        f2bf_rne((acc[mi][ni][r] + bnv[ni]) * qscale);
                }
            }
        }
    } else {
        #pragma unroll
        for (int mi = 0; mi < 4; ++mi) {
            #pragma unroll
            for (int ni = 0; ni < 4; ++ni) {
                const int n = n0 + wn + ni * 16 + l15;
                const int hh = n >> 6, dh = n & 63;
                const int mb = m0 + wm + mi * 16 + (g << 2);
                const int bi = mb >> 11, s = mb & (NS - 1);
                ushort4 pk;
                pk.x = f2bf_rne(acc[mi][ni][0] + bnv[ni]);
                pk.y = f2bf_rne(acc[mi][ni][1] + bnv[ni]);
                pk.z = f2bf_rne(acc[mi][ni][2] + bnv[ni]);
                pk.w = f2bf_rne(acc[mi][ni][3] + bnv[ni]);
                *(ushort4*)&VT[((size_t)(bi * 8 + hh) * 64 + dh) * 2048 + s] = pk;
            }
        }
    }
}

// ---------------------------------------------------------------------------
// Kernel 2: flash attention, S^T formulation, 1-tile software pipeline.
// Per iteration t: (1) issue V loads (tile t) + K loads (tile t) to regs;
// (2) softmax + Ps roundtrip + PV of tile t-1 (~300cy, hides the L2
// latency of step 1's loads); (3) S^T MFMA of tile t from the now-landed
// K regs; (4) ds_write V regs -> Vt[t&1] (double-buffered); (5) ONE
// __syncthreads. PV of tile t-1 reads Vt[(t-1)&1] (written 2 barriers
// ago, overwritten only after this iteration's barrier). Ps stays
// wave-private (no barrier ever). Main-loop softmax is always a FULL tile
// (t-1 <= T-2): masking lives only in the epilogue. Denominator l via
// ones-MFMA. ctx written bf16 hi/lo; hi overwrites Qb in place.
// ---------------------------------------------------------------------------
__global__ __launch_bounds__(256) void attn_kernel(
    ush* __restrict__ Qb, const ush* __restrict__ Kb,
    const ush* __restrict__ VT, const int* __restrict__ lens,
    ush* __restrict__ ctx_lo)
{
    __shared__ ush Ps[64 * 72];     // [q_local][key], stride 72, wave-private rows
    __shared__ ush Vt[2 * 4624];    // double-buffered: [dv][key], addr = dv*72+((dv>>4)<<3)+key

    const int tid = threadIdx.x;
    const int w = tid >> 6, l = tid & 63;
    const int l15 = l & 15, g = l >> 4;

    const int id = blockIdx.x;
    const int h = id & 7, qt = (id >> 3) & 31, b = id >> 8;
    const int L = lens[b];
    const int q0 = qt << 6;
    const size_t bh = ((size_t)b * 8 + h) * 2048;

    // Q B-fragments (held all kernel)
    const ush* qptr = Qb + (bh + q0 + w * 16 + l15) * 64 + g * 8;
    const bf16x8 qf0 = *(const bf16x8*)(qptr);
    const bf16x8 qf1 = *(const bf16x8*)(qptr + 32);

    const ush* kbase = Kb + (bh + l15) * 64 + g * 8;

    // V^T staging: thread owns dv row, 16-key segment
    const int dv = tid >> 2, seg = (tid & 3) << 4;
    const ush* vbase = VT + bh * 64 + (size_t)dv * 2048 + seg;
    const int vt_off = dv * 72 + ((dv >> 4) << 3) + seg;

    // Ps pointers (this thread; wave-private rows)
    ush* psw = &Ps[(w * 16 + l15) * 72 + (g << 2)];        // P^T write slot
    const ush* pp = &Ps[(w * 16 + l15) * 72 + g * 8];      // A-frag read slot

    // constant ones B-fragment for the l-MFMA (bf16 1.0 = 0x3F80)
    bf16x8 ones;
    #pragma unroll
    for (int j = 0; j < 8; ++j) ones[j] = (short)0x3F80;

    f32x4 o[4];
    f32x4 ol = (f32x4)(0.0f);   // ol[r] = sum_k P[q=g*4+r][k]
    #pragma unroll
    for (int i = 0; i < 4; ++i) o[i] = (f32x4)(0.0f);

    f32x4 sp[4];                // scores of the in-flight (previous) tile
    const int T = (L + 63) >> 6;

    // ---- prologue: tile 0 ----
    {
        const uint4 v0 = *(const uint4*)(vbase);
        const uint4 v1 = *(const uint4*)(vbase + 8);
        #pragma unroll
        for (int st = 0; st < 4; ++st) sp[st] = (f32x4)(0.0f);
        __builtin_amdgcn_s_setprio(1);
        #pragma unroll
        for (int st = 0; st < 4; ++st) {
            const bf16x8 kf0 = *(const bf16x8*)(kbase + st * 1024);
            const bf16x8 kf1 = *(const bf16x8*)(kbase + st * 1024 + 32);
            sp[st] = __builtin_amdgcn_mfma_f32_16x16x32_bf16(kf0, qf0, sp[st], 0, 0, 0);
            sp[st] = __builtin_amdgcn_mfma_f32_16x16x32_bf16(kf1, qf1, sp[st], 0, 0, 0);
        }
        __builtin_amdgcn_s_setprio(0);
        ush* dst = &Vt[vt_off];   // buffer 0
        *(uint4*)dst = v0;
        *(uint4*)(dst + 8) = v1;
        __syncthreads();
    }

    // softmax + Ps + PV for a completed tile (scores in sp)
    auto finish = [&](const ush* vb, bool masked, int kb0) {
        uint2 pk[4];
        #pragma unroll
        for (int st = 0; st < 4; ++st) {
            float p[4];
            #pragma unroll
            for (int r = 0; r < 4; ++r) {
                float e = EXP2F(sp[st][r]);
                if (masked) {
                    const int key = kb0 + st * 16 + (g << 2) + r;
                    e = (key < L) ? e : 0.0f;
                }
                p[r] = e;
            }
            pk[st].x = cvt_pk_bf16(p[0], p[1]);
            pk[st].y = cvt_pk_bf16(p[2], p[3]);
        }
        #pragma unroll
        for (int st = 0; st < 4; ++st)
            *(uint2*)(psw + st * 16) = pk[st];
        const bf16x8 pf0 = *(const bf16x8*)(pp);
        const bf16x8 pf1 = *(const bf16x8*)(pp + 32);
        __builtin_amdgcn_s_setprio(1);
        ol = __builtin_amdgcn_mfma_f32_16x16x32_bf16(pf0, ones, ol, 0, 0, 0);
        ol = __builtin_amdgcn_mfma_f32_16x16x32_bf16(pf1, ones, ol, 0, 0, 0);
        #pragma unroll
        for (int st2 = 0; st2 < 4; ++st2) {
            const ush* vp = vb + (st2 * 16 + l15) * 72 + (st2 << 3) + g * 8;
            const bf16x8 vf0 = *(const bf16x8*)(vp);
            const bf16x8 vf1 = *(const bf16x8*)(vp + 32);
            o[st2] = __builtin_amdgcn_mfma_f32_16x16x32_bf16(pf0, vf0, o[st2], 0, 0, 0);
            o[st2] = __builtin_amdgcn_mfma_f32_16x16x32_bf16(pf1, vf1, o[st2], 0, 0, 0);
        }
        __builtin_amdgcn_s_setprio(0);
    };

    // ---- main loop: tiles 1..T-1 (finish tile t-1, compute tile t) ----
    for (int t = 1; t < T; ++t) {
        const int k0 = t << 6;
        // early-issue: V tile t + K tile t (land under finish() below)
        const uint4 nv0 = *(const uint4*)(vbase + k0);
        const uint4 nv1 = *(const uint4*)(vbase + k0 + 8);
        bf16x8 kf[8];
        const ush* kp = kbase + (size_t)k0 * 64;
        #pragma unroll
        for (int st = 0; st < 4; ++st) {
            kf[2 * st]     = *(const bf16x8*)(kp + st * 1024);
            kf[2 * st + 1] = *(const bf16x8*)(kp + st * 1024 + 32);
        }

        // finish tile t-1 (always FULL: t-1 <= T-2)
        finish(&Vt[((t & 1) ^ 1) * 4624], false, 0);

        // S^T MFMA tile t
        #pragma unroll
        for (int st = 0; st < 4; ++st) sp[st] = (f32x4)(0.0f);
        __builtin_amdgcn_s_setprio(1);
        #pragma unroll
        for (int st = 0; st < 4; ++st) {
            sp[st] = __builtin_amdgcn_mfma_f32_16x16x32_bf16(kf[2 * st], qf0, sp[st], 0, 0, 0);
            sp[st] = __builtin_amdgcn_mfma_f32_16x16x32_bf16(kf[2 * st + 1], qf1, sp[st], 0, 0, 0);
        }
        __builtin_amdgcn_s_setprio(0);

        // stage V tile t into buf[t&1] (reads of this buf ended before last barrier)
        ush* dst = &Vt[(t & 1) * 4624 + vt_off];
        *(uint4*)dst = nv0;
        *(uint4*)(dst + 8) = nv1;
        __syncthreads();
    }

    // ---- epilogue: finish tile T-1 (the only possibly-partial tile) ----
    finish(&Vt[((T - 1) & 1) * 4624], true, (T - 1) << 6);

    #pragma unroll
    for (int r = 0; r < 4; ++r) {
        const float inv = 1.0f / ol[r];   // l for q = g*4+r, lane-local
        const size_t row = bh + q0 + w * 16 + (g << 2) + r;
        #pragma unroll
        for (int st2 = 0; st2 < 4; ++st2) {
            const float val = o[st2][r] * inv;
            const ush hi = f2bf_rne(val);
            const ush lo = f2bf_rne(val - bf2f(hi));
            Qb[row * 64 + st2 * 16 + l15] = hi;        // ctx_hi in place
            ctx_lo[row * 64 + st2 * 16 + l15] = lo;
        }
    }
}

// ---------------------------------------------------------------------------
// Kernel 3: out = ctx @ Wo^T + bo, 3-term split bf16 MFMA
// (hi·hi + lo·hi + hi·lo ~ fp32 accuracy). ctx gathered from (B,H,S,DH).
// ---------------------------------------------------------------------------
__global__ __launch_bounds__(256) void out_gemm_kernel(
    const ush* __restrict__ ctx_hi, const ush* __restrict__ ctx_lo,
    const ush* __restrict__ wo_hi, const ush* __restrict__ wo_lo,
    const float* __restrict__ bo, float* __restrict__ out)
{
    __shared__ ush Ah[4096], Al[4096], Bh[4096], Bl[4096];

    const int t = threadIdx.x;
    const int w = t >> 6, l = t & 63;
    const int l15 = l & 15, g = l >> 4;
    const int m0 = blockIdx.x * 128, n0 = blockIdx.y * 128;
    const int wm = (w & 1) << 6, wn = (w >> 1) << 6;

    const int srow = l >> 2;
    const int sg   = (l & 3) ^ ((srow + (srow >> 2)) & 3);
    const int fsw  = (g ^ ((l15 + (l15 >> 2)) & 3)) << 3;
    const int c0   = w * 2;

    f32x4 acc[4][4];
    #pragma unroll
    for (int i = 0; i < 4; ++i)
        #pragma unroll
        for (int j = 0; j < 4; ++j) acc[i][j] = (f32x4)(0.0f);

    for (int kt = 0; kt < 512; kt += 32) {
        __syncthreads();   // previous frag reads complete
        #pragma unroll
        for (int cc = 0; cc < 2; ++cc) {
            const int c = c0 + cc;
            // ctx rows: token m; k = h*64 + dh (BK=32 stays inside one head)
            const int m = m0 + c * 16 + srow;
            const int k = kt + sg * 8;
            const size_t ga = ((size_t)((m >> 11) * 8 + (k >> 6)) * 2048 + (m & (NS - 1))) * 64 + (k & 63);
            GLL16(&ctx_hi[ga], &Ah[c * 512 + l * 8]);
            GLL16(&ctx_lo[ga], &Al[c * 512 + l * 8]);
            const size_t gb = (size_t)(n0 + c * 16 + srow) * 512 + kt + sg * 8;
            GLL16(&wo_hi[gb], &Bh[c * 512 + l * 8]);
            GLL16(&wo_lo[gb], &Bl[c * 512 + l * 8]);
        }
        __syncthreads();   // staged

        bf16x8 ah[4], al[4], bh4[4], bl4[4];
        #pragma unroll
        for (int mi = 0; mi < 4; ++mi) {
            const int off = (((w & 1) << 2) + mi) * 512 + l15 * 32 + fsw;
            ah[mi] = *(const bf16x8*)&Ah[off];
            al[mi] = *(const bf16x8*)&Al[off];
        }
        #pragma unroll
        for (int ni = 0; ni < 4; ++ni) {
            const int off = (((w >> 1) << 2) + ni) * 512 + l15 * 32 + fsw;
            bh4[ni] = *(const bf16x8*)&Bh[off];
            bl4[ni] = *(const bf16x8*)&Bl[off];
        }
        #pragma unroll
        for (int mi = 0; mi < 4; ++mi)
            #pragma unroll
            for (int ni = 0; ni < 4; ++ni) {
                acc[mi][ni] = __builtin_amdgcn_mfma_f32_16x16x32_bf16(ah[mi], bh4[ni], acc[mi][ni], 0, 0, 0);
                acc[mi][ni] = __builtin_amdgcn_mfma_f32_16x16x32_bf16(al[mi], bh4[ni], acc[mi][ni], 0, 0, 0);
                acc[mi][ni] = __builtin_amdgcn_mfma_f32_16x16x32_bf16(ah[mi], bl4[ni], acc[mi][ni], 0, 0, 0);
            }
    }

    float bov[4];
    #pragma unroll
    for (int ni = 0; ni < 4; ++ni) bov[ni] = bo[n0 + wn + ni * 16 + l15];

    #pragma unroll
    for (int mi = 0; mi < 4; ++mi)
        #pragma unroll
        for (int ni = 0; ni < 4; ++ni) {
            const int n = n0 + wn + ni * 16 + l15;
            #pragma unroll
            for (int r = 0; r < 4; ++r) {
                const int m = m0 + wm + mi * 16 + (g << 2) + r;
                out[(size_t)m * 512 + n] = acc[mi][ni][r] + bov[ni];
            }
        }
}

// ---------------------------------------------------------------------------
extern "C" void kernel_launch(void* const* d_in, const int* in_sizes, int n_in,
                              void* d_out, int out_size, void* d_ws, size_t ws_size,
                              hipStream_t stream)
{
    const float* xq   = (const float*)d_in[0];
    const float* xk   = (const float*)d_in[1];
    const float* xv   = (const float*)d_in[2];
    const float* Wq   = (const float*)d_in[3];
    const float* bq   = (const float*)d_in[4];
    const float* Wk   = (const float*)d_in[5];
    const float* bk   = (const float*)d_in[6];
    const float* Wv   = (const float*)d_in[7];
    const float* bv   = (const float*)d_in[8];
    const float* Wo   = (const float*)d_in[9];
    const float* bo   = (const float*)d_in[10];
    const int*   lens = (const int*)d_in[11];
    float* out = (float*)d_out;

    const size_t elems = (size_t)NB * NHH * NS * NDH;   // 8.39M
    ush* Qb     = (ush*)d_ws;          // bf16 Q (pre-scaled); later ctx_hi in place
    ush* Kb     = Qb + elems;
    ush* VT     = Kb + elems;          // V transposed (B,H,DH,S)
    ush* ctx_lo = VT + elems;
    ush* wbf    = ctx_lo + elems;      // Wq,Wk,Wv bf16 (3*262144)
    ush* wo_hi  = wbf + 3 * 262144;
    ush* wo_lo  = wo_hi + 262144;
    // total: 4*8.39M + 5*262144 shorts = 69.7 MB (< 100.7 MB proven in R1)

    const dim3 blk(256);
    conv_w_kernel<<<dim3(256, 4), blk, 0, stream>>>(Wq, Wk, Wv, Wo, wbf, wo_hi, wo_lo);
    qkv_gemm_kernel<<<dim3(128, 4, 3), blk, 0, stream>>>(
        xq, xk, xv, wbf, bq, bk, bv, Qb, Kb, VT);
    attn_kernel<<<dim3(NB * NHH * (NS / 64)), blk, 0, stream>>>(Qb, Kb, VT, lens, ctx_lo);
    out_gemm_kernel<<<dim3(128, 4), blk, 0, stream>>>(Qb, ctx_lo, wo_hi, wo_lo, bo, out);
}

// Round 5
// 309.834 us; speedup vs baseline: 1.4301x; 1.1453x over previous
//
#include <hip/hip_runtime.h>
#include <math.h>

#define NB 8
#define NS 2048
#define ND 512
#define NHH 8
#define NDH 64

typedef __attribute__((ext_vector_type(4))) float f32x4;
typedef __attribute__((ext_vector_type(8))) short bf16x8;
typedef unsigned short ush;

__device__ inline ush f2bf_rne(float f) {
    unsigned u = __float_as_uint(f);
    unsigned r = u + 0x7FFFu + ((u >> 16) & 1u);
    return (ush)(r >> 16);
}
__device__ inline float bf2f(ush h) { return __uint_as_float(((unsigned)h) << 16); }

// packed f32x2 -> bf16x2 (RNE), single VALU instruction
__device__ inline unsigned cvt_pk_bf16(float lo, float hi) {
    unsigned r;
    asm("v_cvt_pk_bf16_f32 %0, %1, %2" : "=v"(r) : "v"(lo), "v"(hi));
    return r;
}

#if defined(__has_builtin)
#if __has_builtin(__builtin_amdgcn_exp2f)
#define EXP2F(x) __builtin_amdgcn_exp2f(x)
#else
#define EXP2F(x) exp2f(x)
#endif
#else
#define EXP2F(x) exp2f(x)
#endif

// async global->LDS, 16B per lane (global_load_lds_dwordx4)
#define GLL16(gp, lp) __builtin_amdgcn_global_load_lds( \
    (const __attribute__((address_space(1))) unsigned int*)(gp), \
    (__attribute__((address_space(3))) unsigned int*)(lp), 16, 0, 0)

// ---------------------------------------------------------------------------
// Kernel 0: weight conversion. y<3: Wq/Wk/Wv -> bf16. y==3: Wo -> hi/lo bf16.
// ---------------------------------------------------------------------------
__global__ __launch_bounds__(256) void conv_w_kernel(
    const float* __restrict__ Wq, const float* __restrict__ Wk,
    const float* __restrict__ Wv, const float* __restrict__ Wo,
    ush* __restrict__ wbf, ush* __restrict__ wo_hi, ush* __restrict__ wo_lo)
{
    const int y = blockIdx.y;
    const int i = (blockIdx.x * 256 + threadIdx.x) * 4;
    if (y < 3) {
        const float* src = (y == 0) ? Wq : (y == 1) ? Wk : Wv;
        const float4 v = *(const float4*)&src[i];
        ushort4 o;
        o.x = f2bf_rne(v.x); o.y = f2bf_rne(v.y);
        o.z = f2bf_rne(v.z); o.w = f2bf_rne(v.w);
        *(ushort4*)&wbf[y * 262144 + i] = o;
    } else {
        const float4 v = *(const float4*)&Wo[i];
        ushort4 hi, lo;
        hi.x = f2bf_rne(v.x); lo.x = f2bf_rne(v.x - bf2f(hi.x));
        hi.y = f2bf_rne(v.y); lo.y = f2bf_rne(v.y - bf2f(hi.y));
        hi.z = f2bf_rne(v.z); lo.z = f2bf_rne(v.z - bf2f(hi.z));
        hi.w = f2bf_rne(v.w); lo.w = f2bf_rne(v.w - bf2f(hi.w));
        *(ushort4*)&wo_hi[i] = hi;
        *(ushort4*)&wo_lo[i] = lo;
    }
}

// ---------------------------------------------------------------------------
// Kernel 1: QKV projections via bf16 MFMA. C = X @ W^T + b.
// 128x128 tile, BK=32, 4 waves (2x2 of 64x64), 16x16x32 MFMA.
// 2-PHASE DOUBLE-BUFFERED: one barrier per K-iter; loads for kt+32 are
// issued before kt's MFMAs so the ~500cy load latency hides under compute
// instead of being drained cold at the barrier.
// LDS swizzle per 16-row chunk as before (quarter-wave bank floor).
// A (x fp32) converted in-staging (after MFMAs); B (bf16) via GLL16.
// Epilogue: z=0 Q (scaled 0.125*log2e); z=1 K; z=2 V transposed (B,H,DH,S).
// ---------------------------------------------------------------------------
__global__ __launch_bounds__(256) void qkv_gemm_kernel(
    const float* __restrict__ xq, const float* __restrict__ xk, const float* __restrict__ xv,
    const ush* __restrict__ wbf,
    const float* __restrict__ bq, const float* __restrict__ bk, const float* __restrict__ bv,
    ush* __restrict__ Qb, ush* __restrict__ Kb, ush* __restrict__ VT)
{
    __shared__ ush As[2][4096];   // 8 chunks x 512 shorts = 8 KB per buffer
    __shared__ ush Bs[2][4096];

    const int z = blockIdx.z;
    const float* X    = (z == 0) ? xq : (z == 1) ? xk : xv;
    const ush*   W    = wbf + z * 262144;
    const float* bias = (z == 0) ? bq : (z == 1) ? bk : bv;

    const int t = threadIdx.x;
    const int w = t >> 6, l = t & 63;
    const int l15 = l & 15, g = l >> 4;
    const int m0 = blockIdx.x * 128, n0 = blockIdx.y * 128;
    const int wm = (w & 1) << 6, wn = (w >> 1) << 6;

    const int srow = l >> 2;                                   // row within chunk
    const int sg   = (l & 3) ^ ((srow + (srow >> 2)) & 3);     // staged k-group
    const int fsw  = (g ^ ((l15 + (l15 >> 2)) & 3)) << 3;      // frag-read swizzle (shorts)
    const int c0   = w * 2;                                    // this wave's chunks

    f32x4 acc[4][4];
    #pragma unroll
    for (int i = 0; i < 4; ++i)
        #pragma unroll
        for (int j = 0; j < 4; ++j) acc[i][j] = (f32x4)(0.0f);

    // ---- prologue: stage kt=0 into buffer 0 ----
    {
        const size_t ar0 = (size_t)(m0 + c0 * 16 + srow) * 512 + sg * 8;
        const size_t ar1 = (size_t)(m0 + (c0 + 1) * 16 + srow) * 512 + sg * 8;
        const float4 a0 = *(const float4*)&X[ar0];
        const float4 a1 = *(const float4*)&X[ar0 + 4];
        const float4 a2 = *(const float4*)&X[ar1];
        const float4 a3 = *(const float4*)&X[ar1 + 4];
        GLL16(&W[(size_t)(n0 + c0 * 16 + srow) * 512 + sg * 8], &Bs[0][c0 * 512 + l * 8]);
        GLL16(&W[(size_t)(n0 + (c0 + 1) * 16 + srow) * 512 + sg * 8], &Bs[0][(c0 + 1) * 512 + l * 8]);
        uint4 u0, u1;
        u0.x = (unsigned)f2bf_rne(a0.x) | ((unsigned)f2bf_rne(a0.y) << 16);
        u0.y = (unsigned)f2bf_rne(a0.z) | ((unsigned)f2bf_rne(a0.w) << 16);
        u0.z = (unsigned)f2bf_rne(a1.x) | ((unsigned)f2bf_rne(a1.y) << 16);
        u0.w = (unsigned)f2bf_rne(a1.z) | ((unsigned)f2bf_rne(a1.w) << 16);
        u1.x = (unsigned)f2bf_rne(a2.x) | ((unsigned)f2bf_rne(a2.y) << 16);
        u1.y = (unsigned)f2bf_rne(a2.z) | ((unsigned)f2bf_rne(a2.w) << 16);
        u1.z = (unsigned)f2bf_rne(a3.x) | ((unsigned)f2bf_rne(a3.y) << 16);
        u1.w = (unsigned)f2bf_rne(a3.z) | ((unsigned)f2bf_rne(a3.w) << 16);
        *(uint4*)&As[0][c0 * 512 + l * 8] = u0;
        *(uint4*)&As[0][(c0 + 1) * 512 + l * 8] = u1;
        __syncthreads();
    }

    for (int ki = 0; ki < 16; ++ki) {
        const int buf = ki & 1;
        const int ktn = (ki + 1) * 32;   // next tile's k offset
        float4 a0, a1, a2, a3;
        if (ki < 15) {
            // issue next tile's loads FIRST (span this tile's MFMAs)
            const size_t ar0 = (size_t)(m0 + c0 * 16 + srow) * 512 + ktn + sg * 8;
            const size_t ar1 = (size_t)(m0 + (c0 + 1) * 16 + srow) * 512 + ktn + sg * 8;
            a0 = *(const float4*)&X[ar0];
            a1 = *(const float4*)&X[ar0 + 4];
            a2 = *(const float4*)&X[ar1];
            a3 = *(const float4*)&X[ar1 + 4];
            GLL16(&W[(size_t)(n0 + c0 * 16 + srow) * 512 + ktn + sg * 8], &Bs[buf ^ 1][c0 * 512 + l * 8]);
            GLL16(&W[(size_t)(n0 + (c0 + 1) * 16 + srow) * 512 + ktn + sg * 8], &Bs[buf ^ 1][(c0 + 1) * 512 + l * 8]);
        }

        // compute current tile
        bf16x8 af[4], bfr[4];
        #pragma unroll
        for (int mi = 0; mi < 4; ++mi)
            af[mi] = *(const bf16x8*)&As[buf][(((w & 1) << 2) + mi) * 512 + l15 * 32 + fsw];
        #pragma unroll
        for (int ni = 0; ni < 4; ++ni)
            bfr[ni] = *(const bf16x8*)&Bs[buf][(((w >> 1) << 2) + ni) * 512 + l15 * 32 + fsw];
        #pragma unroll
        for (int mi = 0; mi < 4; ++mi)
            #pragma unroll
            for (int ni = 0; ni < 4; ++ni)
                acc[mi][ni] = __builtin_amdgcn_mfma_f32_16x16x32_bf16(af[mi], bfr[ni], acc[mi][ni], 0, 0, 0);

        if (ki < 15) {
            // A convert + write to alternate buffer (after MFMAs: loads had
            // the whole MFMA phase to land)
            uint4 u0, u1;
            u0.x = (unsigned)f2bf_rne(a0.x) | ((unsigned)f2bf_rne(a0.y) << 16);
            u0.y = (unsigned)f2bf_rne(a0.z) | ((unsigned)f2bf_rne(a0.w) << 16);
            u0.z = (unsigned)f2bf_rne(a1.x) | ((unsigned)f2bf_rne(a1.y) << 16);
            u0.w = (unsigned)f2bf_rne(a1.z) | ((unsigned)f2bf_rne(a1.w) << 16);
            u1.x = (unsigned)f2bf_rne(a2.x) | ((unsigned)f2bf_rne(a2.y) << 16);
            u1.y = (unsigned)f2bf_rne(a2.z) | ((unsigned)f2bf_rne(a2.w) << 16);
            u1.z = (unsigned)f2bf_rne(a3.x) | ((unsigned)f2bf_rne(a3.y) << 16);
            u1.w = (unsigned)f2bf_rne(a3.z) | ((unsigned)f2bf_rne(a3.w) << 16);
            *(uint4*)&As[buf ^ 1][c0 * 512 + l * 8] = u0;
            *(uint4*)&As[buf ^ 1][(c0 + 1) * 512 + l * 8] = u1;
        }
        __syncthreads();   // drains vmcnt (GLL16) + lgkm; protects buf reuse
    }

    const float qscale = (z == 0) ? 0.18033688011112042f : 1.0f;   // 0.125*log2(e)
    float bnv[4];
    #pragma unroll
    for (int ni = 0; ni < 4; ++ni) bnv[ni] = bias[n0 + wn + ni * 16 + l15];

    if (z < 2) {
        ush* O = (z == 0) ? Qb : Kb;
        #pragma unroll
        for (int mi = 0; mi < 4; ++mi) {
            #pragma unroll
            for (int ni = 0; ni < 4; ++ni) {
                const int n = n0 + wn + ni * 16 + l15;
                const int hh = n >> 6, dh = n & 63;
                #pragma unroll
                for (int r = 0; r < 4; ++r) {
                    const int m = m0 + wm + mi * 16 + (g << 2) + r;
                    const int bi = m >> 11, s = m & (NS - 1);
                    O[((size_t)(bi * 8 + hh) * 2048 + s) * 64 + dh] =
                        f2bf_rne((acc[mi][ni][r] + bnv[ni]) * qscale);
                }
            }
        }
    } else {
        #pragma unroll
        for (int mi = 0; mi < 4; ++mi) {
            #pragma unroll
            for (int ni = 0; ni < 4; ++ni) {
                const int n = n0 + wn + ni * 16 + l15;
                const int hh = n >> 6, dh = n & 63;
                const int mb = m0 + wm + mi * 16 + (g << 2);
                const int bi = mb >> 11, s = mb & (NS - 1);
                ushort4 pk;
                pk.x = f2bf_rne(acc[mi][ni][0] + bnv[ni]);
                pk.y = f2bf_rne(acc[mi][ni][1] + bnv[ni]);
                pk.z = f2bf_rne(acc[mi][ni][2] + bnv[ni]);
                pk.w = f2bf_rne(acc[mi][ni][3] + bnv[ni]);
                *(ushort4*)&VT[((size_t)(bi * 8 + hh) * 64 + dh) * 2048 + s] = pk;
            }
        }
    }
}

// ---------------------------------------------------------------------------
// Kernel 2: flash attention, S^T formulation, 2 Q-TILES PER BLOCK (128 q
// rows), 1-tile software pipeline. Per key-tile: kf/v loads for tile t
// issued first; finish(t-1) runs softmax+Ps+PV for BOTH q-tiles sharing
// ONE set of V-fragment LDS reads (V reads, V staging, K loads, barriers
// all amortized 2x vs one q-tile/block); then S^T MFMA (t) for both
// q-tiles; V staged to Vt[t&1]; one barrier. Ps wave-private. Denominator
// via ones-MFMA. Masking only in the epilogue tile.
// ---------------------------------------------------------------------------
__global__ __launch_bounds__(256) void attn_kernel(
    ush* __restrict__ Qb, const ush* __restrict__ Kb,
    const ush* __restrict__ VT, const int* __restrict__ lens,
    ush* __restrict__ ctx_lo)
{
    __shared__ ush Ps[128 * 72];    // [q_local][key] two q-tiles, wave-private rows
    __shared__ ush Vt[2 * 4624];    // double-buffered [dv][key]

    const int tid = threadIdx.x;
    const int w = tid >> 6, l = tid & 63;
    const int l15 = l & 15, g = l >> 4;

    const int id = blockIdx.x;
    const int h = id & 7, qt = (id >> 3) & 15, b = id >> 7;
    const int L = lens[b];
    const int q0 = qt << 7;
    const size_t bh = ((size_t)b * 8 + h) * 2048;

    // Q B-fragments, two q-tiles (rows q0+w*16.. and q0+64+w*16..)
    const ush* qptr = Qb + (bh + q0 + w * 16 + l15) * 64 + g * 8;
    const bf16x8 qfa0 = *(const bf16x8*)(qptr);
    const bf16x8 qfa1 = *(const bf16x8*)(qptr + 32);
    const bf16x8 qfb0 = *(const bf16x8*)(qptr + 64 * 64);
    const bf16x8 qfb1 = *(const bf16x8*)(qptr + 64 * 64 + 32);

    const ush* kbase = Kb + (bh + l15) * 64 + g * 8;

    // V^T staging: thread owns dv row, 16-key segment
    const int dv = tid >> 2, seg = (tid & 3) << 4;
    const ush* vbase = VT + bh * 64 + (size_t)dv * 2048 + seg;
    const int vt_off = dv * 72 + ((dv >> 4) << 3) + seg;

    // Ps pointers (wave-private rows; +64*72 for q-tile b)
    ush* psw_a = &Ps[(w * 16 + l15) * 72 + (g << 2)];
    const ush* pp_a = &Ps[(w * 16 + l15) * 72 + g * 8];
    ush* psw_b = psw_a + 64 * 72;
    const ush* pp_b = pp_a + 64 * 72;

    // constant ones B-fragment for the l-MFMA (bf16 1.0 = 0x3F80)
    bf16x8 ones;
    #pragma unroll
    for (int j = 0; j < 8; ++j) ones[j] = (short)0x3F80;

    f32x4 oa[4], ob[4];
    f32x4 ola = (f32x4)(0.0f), olb = (f32x4)(0.0f);
    #pragma unroll
    for (int i = 0; i < 4; ++i) { oa[i] = (f32x4)(0.0f); ob[i] = (f32x4)(0.0f); }

    f32x4 spa[4], spb[4];       // in-flight scores, both q-tiles
    const int T = (L + 63) >> 6;

    // ---- prologue: tile 0 scores + V0 staging ----
    {
        const uint4 v0 = *(const uint4*)(vbase);
        const uint4 v1 = *(const uint4*)(vbase + 8);
        #pragma unroll
        for (int st = 0; st < 4; ++st) { spa[st] = (f32x4)(0.0f); spb[st] = (f32x4)(0.0f); }
        __builtin_amdgcn_s_setprio(1);
        #pragma unroll
        for (int st = 0; st < 4; ++st) {
            const bf16x8 kf0 = *(const bf16x8*)(kbase + st * 1024);
            const bf16x8 kf1 = *(const bf16x8*)(kbase + st * 1024 + 32);
            spa[st] = __builtin_amdgcn_mfma_f32_16x16x32_bf16(kf0, qfa0, spa[st], 0, 0, 0);
            spa[st] = __builtin_amdgcn_mfma_f32_16x16x32_bf16(kf1, qfa1, spa[st], 0, 0, 0);
            spb[st] = __builtin_amdgcn_mfma_f32_16x16x32_bf16(kf0, qfb0, spb[st], 0, 0, 0);
            spb[st] = __builtin_amdgcn_mfma_f32_16x16x32_bf16(kf1, qfb1, spb[st], 0, 0, 0);
        }
        __builtin_amdgcn_s_setprio(0);
        ush* dst = &Vt[vt_off];
        *(uint4*)dst = v0;
        *(uint4*)(dst + 8) = v1;
        __syncthreads();
    }

    // finish a completed tile (both q-tiles, shared V-fragment reads)
    auto finish = [&](const ush* vb, bool masked, int kb0) {
        uint2 pka[4], pkb[4];
        #pragma unroll
        for (int st = 0; st < 4; ++st) {
            float pa[4], pb[4];
            #pragma unroll
            for (int r = 0; r < 4; ++r) {
                float ea = EXP2F(spa[st][r]);
                float eb = EXP2F(spb[st][r]);
                if (masked) {
                    const int key = kb0 + st * 16 + (g << 2) + r;
                    ea = (key < L) ? ea : 0.0f;
                    eb = (key < L) ? eb : 0.0f;
                }
                pa[r] = ea; pb[r] = eb;
            }
            pka[st].x = cvt_pk_bf16(pa[0], pa[1]);
            pka[st].y = cvt_pk_bf16(pa[2], pa[3]);
            pkb[st].x = cvt_pk_bf16(pb[0], pb[1]);
            pkb[st].y = cvt_pk_bf16(pb[2], pb[3]);
        }
        #pragma unroll
        for (int st = 0; st < 4; ++st) {
            *(uint2*)(psw_a + st * 16) = pka[st];
            *(uint2*)(psw_b + st * 16) = pkb[st];
        }
        const bf16x8 pfa0 = *(const bf16x8*)(pp_a);
        const bf16x8 pfa1 = *(const bf16x8*)(pp_a + 32);
        const bf16x8 pfb0 = *(const bf16x8*)(pp_b);
        const bf16x8 pfb1 = *(const bf16x8*)(pp_b + 32);
        __builtin_amdgcn_s_setprio(1);
        ola = __builtin_amdgcn_mfma_f32_16x16x32_bf16(pfa0, ones, ola, 0, 0, 0);
        ola = __builtin_amdgcn_mfma_f32_16x16x32_bf16(pfa1, ones, ola, 0, 0, 0);
        olb = __builtin_amdgcn_mfma_f32_16x16x32_bf16(pfb0, ones, olb, 0, 0, 0);
        olb = __builtin_amdgcn_mfma_f32_16x16x32_bf16(pfb1, ones, olb, 0, 0, 0);
        #pragma unroll
        for (int st2 = 0; st2 < 4; ++st2) {
            const ush* vp = vb + (st2 * 16 + l15) * 72 + (st2 << 3) + g * 8;
            const bf16x8 vf0 = *(const bf16x8*)(vp);
            const bf16x8 vf1 = *(const bf16x8*)(vp + 32);
            oa[st2] = __builtin_amdgcn_mfma_f32_16x16x32_bf16(pfa0, vf0, oa[st2], 0, 0, 0);
            oa[st2] = __builtin_amdgcn_mfma_f32_16x16x32_bf16(pfa1, vf1, oa[st2], 0, 0, 0);
            ob[st2] = __builtin_amdgcn_mfma_f32_16x16x32_bf16(pfb0, vf0, ob[st2], 0, 0, 0);
            ob[st2] = __builtin_amdgcn_mfma_f32_16x16x32_bf16(pfb1, vf1, ob[st2], 0, 0, 0);
        }
        __builtin_amdgcn_s_setprio(0);
    };

    // ---- main loop: tiles 1..T-1 ----
    for (int t = 1; t < T; ++t) {
        const int k0 = t << 6;
        // early-issue K then V for tile t
        bf16x8 kf[8];
        const ush* kp = kbase + (size_t)k0 * 64;
        #pragma unroll
        for (int st = 0; st < 4; ++st) {
            kf[2 * st]     = *(const bf16x8*)(kp + st * 1024);
            kf[2 * st + 1] = *(const bf16x8*)(kp + st * 1024 + 32);
        }
        const uint4 nv0 = *(const uint4*)(vbase + k0);
        const uint4 nv1 = *(const uint4*)(vbase + k0 + 8);

        // finish tile t-1 (always FULL)
        finish(&Vt[((t & 1) ^ 1) * 4624], false, 0);

        // S^T MFMA tile t, both q-tiles
        #pragma unroll
        for (int st = 0; st < 4; ++st) { spa[st] = (f32x4)(0.0f); spb[st] = (f32x4)(0.0f); }
        __builtin_amdgcn_s_setprio(1);
        #pragma unroll
        for (int st = 0; st < 4; ++st) {
            spa[st] = __builtin_amdgcn_mfma_f32_16x16x32_bf16(kf[2 * st], qfa0, spa[st], 0, 0, 0);
            spa[st] = __builtin_amdgcn_mfma_f32_16x16x32_bf16(kf[2 * st + 1], qfa1, spa[st], 0, 0, 0);
            spb[st] = __builtin_amdgcn_mfma_f32_16x16x32_bf16(kf[2 * st], qfb0, spb[st], 0, 0, 0);
            spb[st] = __builtin_amdgcn_mfma_f32_16x16x32_bf16(kf[2 * st + 1], qfb1, spb[st], 0, 0, 0);
        }
        __builtin_amdgcn_s_setprio(0);

        // stage V tile t
        ush* dst = &Vt[(t & 1) * 4624 + vt_off];
        *(uint4*)dst = nv0;
        *(uint4*)(dst + 8) = nv1;
        __syncthreads();
    }

    // ---- epilogue: finish tile T-1 (possibly partial) ----
    finish(&Vt[((T - 1) & 1) * 4624], true, (T - 1) << 6);

    #pragma unroll
    for (int r = 0; r < 4; ++r) {
        const float inva = 1.0f / ola[r];
        const float invb = 1.0f / olb[r];
        const size_t rowa = bh + q0 + w * 16 + (g << 2) + r;
        const size_t rowb = rowa + 64;
        #pragma unroll
        for (int st2 = 0; st2 < 4; ++st2) {
            const float va = oa[st2][r] * inva;
            const ush ha = f2bf_rne(va);
            Qb[rowa * 64 + st2 * 16 + l15] = ha;
            ctx_lo[rowa * 64 + st2 * 16 + l15] = f2bf_rne(va - bf2f(ha));
            const float vbv = ob[st2][r] * invb;
            const ush hb = f2bf_rne(vbv);
            Qb[rowb * 64 + st2 * 16 + l15] = hb;
            ctx_lo[rowb * 64 + st2 * 16 + l15] = f2bf_rne(vbv - bf2f(hb));
        }
    }
}

// ---------------------------------------------------------------------------
// Kernel 3: out = ctx @ Wo^T + bo, 3-term split bf16 MFMA.
// 2-PHASE DOUBLE-BUFFERED (one barrier/iter, GLL16s for kt+32 issued
// before kt's 48 MFMAs). ctx gathered from (B,H,S,DH).
// ---------------------------------------------------------------------------
__global__ __launch_bounds__(256) void out_gemm_kernel(
    const ush* __restrict__ ctx_hi, const ush* __restrict__ ctx_lo,
    const ush* __restrict__ wo_hi, const ush* __restrict__ wo_lo,
    const float* __restrict__ bo, float* __restrict__ out)
{
    __shared__ ush Ah[2][4096], Al[2][4096], Bh[2][4096], Bl[2][4096];

    const int t = threadIdx.x;
    const int w = t >> 6, l = t & 63;
    const int l15 = l & 15, g = l >> 4;
    const int m0 = blockIdx.x * 128, n0 = blockIdx.y * 128;
    const int wm = (w & 1) << 6, wn = (w >> 1) << 6;

    const int srow = l >> 2;
    const int sg   = (l & 3) ^ ((srow + (srow >> 2)) & 3);
    const int fsw  = (g ^ ((l15 + (l15 >> 2)) & 3)) << 3;
    const int c0   = w * 2;

    f32x4 acc[4][4];
    #pragma unroll
    for (int i = 0; i < 4; ++i)
        #pragma unroll
        for (int j = 0; j < 4; ++j) acc[i][j] = (f32x4)(0.0f);

    // stage one K-tile into buffer `bf`
    auto stage = [&](int bf, int kt) {
        #pragma unroll
        for (int cc = 0; cc < 2; ++cc) {
            const int c = c0 + cc;
            const int m = m0 + c * 16 + srow;
            const int k = kt + sg * 8;
            const size_t ga = ((size_t)((m >> 11) * 8 + (k >> 6)) * 2048 + (m & (NS - 1))) * 64 + (k & 63);
            GLL16(&ctx_hi[ga], &Ah[bf][c * 512 + l * 8]);
            GLL16(&ctx_lo[ga], &Al[bf][c * 512 + l * 8]);
            const size_t gb = (size_t)(n0 + c * 16 + srow) * 512 + kt + sg * 8;
            GLL16(&wo_hi[gb], &Bh[bf][c * 512 + l * 8]);
            GLL16(&wo_lo[gb], &Bl[bf][c * 512 + l * 8]);
        }
    };

    stage(0, 0);
    __syncthreads();

    for (int ki = 0; ki < 16; ++ki) {
        const int buf = ki & 1;
        if (ki < 15) stage(buf ^ 1, (ki + 1) * 32);

        bf16x8 ah[4], al[4], bh4[4], bl4[4];
        #pragma unroll
        for (int mi = 0; mi < 4; ++mi) {
            const int off = (((w & 1) << 2) + mi) * 512 + l15 * 32 + fsw;
            ah[mi] = *(const bf16x8*)&Ah[buf][off];
            al[mi] = *(const bf16x8*)&Al[buf][off];
        }
        #pragma unroll
        for (int ni = 0; ni < 4; ++ni) {
            const int off = (((w >> 1) << 2) + ni) * 512 + l15 * 32 + fsw;
            bh4[ni] = *(const bf16x8*)&Bh[buf][off];
            bl4[ni] = *(const bf16x8*)&Bl[buf][off];
        }
        #pragma unroll
        for (int mi = 0; mi < 4; ++mi)
            #pragma unroll
            for (int ni = 0; ni < 4; ++ni) {
                acc[mi][ni] = __builtin_amdgcn_mfma_f32_16x16x32_bf16(ah[mi], bh4[ni], acc[mi][ni], 0, 0, 0);
                acc[mi][ni] = __builtin_amdgcn_mfma_f32_16x16x32_bf16(al[mi], bh4[ni], acc[mi][ni], 0, 0, 0);
                acc[mi][ni] = __builtin_amdgcn_mfma_f32_16x16x32_bf16(ah[mi], bl4[ni], acc[mi][ni], 0, 0, 0);
            }
        __syncthreads();   // drains this iter's GLL16s; protects buf reuse
    }

    float bov[4];
    #pragma unroll
    for (int ni = 0; ni < 4; ++ni) bov[ni] = bo[n0 + wn + ni * 16 + l15];

    #pragma unroll
    for (int mi = 0; mi < 4; ++mi)
        #pragma unroll
        for (int ni = 0; ni < 4; ++ni) {
            const int n = n0 + wn + ni * 16 + l15;
            #pragma unroll
            for (int r = 0; r < 4; ++r) {
                const int m = m0 + wm + mi * 16 + (g << 2) + r;
                out[(size_t)m * 512 + n] = acc[mi][ni][r] + bov[ni];
            }
        }
}

// ---------------------------------------------------------------------------
extern "C" void kernel_launch(void* const* d_in, const int* in_sizes, int n_in,
                              void* d_out, int out_size, void* d_ws, size_t ws_size,
                              hipStream_t stream)
{
    const float* xq   = (const float*)d_in[0];
    const float* xk   = (const float*)d_in[1];
    const float* xv   = (const float*)d_in[2];
    const float* Wq   = (const float*)d_in[3];
    const float* bq   = (const float*)d_in[4];
    const float* Wk   = (const float*)d_in[5];
    const float* bk   = (const float*)d_in[6];
    const float* Wv   = (const float*)d_in[7];
    const float* bv   = (const float*)d_in[8];
    const float* Wo   = (const float*)d_in[9];
    const float* bo   = (const float*)d_in[10];
    const int*   lens = (const int*)d_in[11];
    float* out = (float*)d_out;

    const size_t elems = (size_t)NB * NHH * NS * NDH;   // 8.39M
    ush* Qb     = (ush*)d_ws;          // bf16 Q (pre-scaled); later ctx_hi in place
    ush* Kb     = Qb + elems;
    ush* VT     = Kb + elems;          // V transposed (B,H,DH,S)
    ush* ctx_lo = VT + elems;
    ush* wbf    = ctx_lo + elems;      // Wq,Wk,Wv bf16 (3*262144)
    ush* wo_hi  = wbf + 3 * 262144;
    ush* wo_lo  = wo_hi + 262144;
    // total: 4*8.39M + 5*262144 shorts = 69.7 MB (< 100.7 MB proven in R1)

    const dim3 blk(256);
    conv_w_kernel<<<dim3(256, 4), blk, 0, stream>>>(Wq, Wk, Wv, Wo, wbf, wo_hi, wo_lo);
    qkv_gemm_kernel<<<dim3(128, 4, 3), blk, 0, stream>>>(
        xq, xk, xv, wbf, bq, bk, bv, Qb, Kb, VT);
    attn_kernel<<<dim3(NB * NHH * (NS / 128)), blk, 0, stream>>>(Qb, Kb, VT, lens, ctx_lo);
    out_gemm_kernel<<<dim3(128, 4), blk, 0, stream>>>(Qb, ctx_lo, wo_hi, wo_lo, bo, out);
}

// Round 6
// 302.018 us; speedup vs baseline: 1.4672x; 1.0259x over previous
//
#include <hip/hip_runtime.h>
#include <math.h>

#define NB 8
#define NS 2048
#define ND 512
#define NHH 8
#define NDH 64

typedef __attribute__((ext_vector_type(4))) float f32x4;
typedef __attribute__((ext_vector_type(8))) short bf16x8;
typedef unsigned short ush;

__device__ inline ush f2bf_rne(float f) {
    unsigned u = __float_as_uint(f);
    unsigned r = u + 0x7FFFu + ((u >> 16) & 1u);
    return (ush)(r >> 16);
}
__device__ inline float bf2f(ush h) { return __uint_as_float(((unsigned)h) << 16); }

// packed f32x2 -> bf16x2 (RNE), single VALU instruction; low half = first arg
__device__ inline unsigned cvt_pk_bf16(float lo, float hi) {
    unsigned r;
    asm("v_cvt_pk_bf16_f32 %0, %1, %2" : "=v"(r) : "v"(lo), "v"(hi));
    return r;
}

#if defined(__has_builtin)
#if __has_builtin(__builtin_amdgcn_exp2f)
#define EXP2F(x) __builtin_amdgcn_exp2f(x)
#else
#define EXP2F(x) exp2f(x)
#endif
#else
#define EXP2F(x) exp2f(x)
#endif

// async global->LDS, 16B per lane (global_load_lds_dwordx4)
#define GLL16(gp, lp) __builtin_amdgcn_global_load_lds( \
    (const __attribute__((address_space(1))) unsigned int*)(gp), \
    (__attribute__((address_space(3))) unsigned int*)(lp), 16, 0, 0)

// ---------------------------------------------------------------------------
// Kernel 0: weight conversion. y<3: Wq/Wk/Wv -> bf16. y==3: Wo -> hi/lo bf16.
// ---------------------------------------------------------------------------
__global__ __launch_bounds__(256) void conv_w_kernel(
    const float* __restrict__ Wq, const float* __restrict__ Wk,
    const float* __restrict__ Wv, const float* __restrict__ Wo,
    ush* __restrict__ wbf, ush* __restrict__ wo_hi, ush* __restrict__ wo_lo)
{
    const int y = blockIdx.y;
    const int i = (blockIdx.x * 256 + threadIdx.x) * 4;
    if (y < 3) {
        const float* src = (y == 0) ? Wq : (y == 1) ? Wk : Wv;
        const float4 v = *(const float4*)&src[i];
        ushort4 o;
        o.x = f2bf_rne(v.x); o.y = f2bf_rne(v.y);
        o.z = f2bf_rne(v.z); o.w = f2bf_rne(v.w);
        *(ushort4*)&wbf[y * 262144 + i] = o;
    } else {
        const float4 v = *(const float4*)&Wo[i];
        ushort4 hi, lo;
        hi.x = f2bf_rne(v.x); lo.x = f2bf_rne(v.x - bf2f(hi.x));
        hi.y = f2bf_rne(v.y); lo.y = f2bf_rne(v.y - bf2f(hi.y));
        hi.z = f2bf_rne(v.z); lo.z = f2bf_rne(v.z - bf2f(hi.z));
        hi.w = f2bf_rne(v.w); lo.w = f2bf_rne(v.w - bf2f(hi.w));
        *(ushort4*)&wo_hi[i] = hi;
        *(ushort4*)&wo_lo[i] = lo;
    }
}

// ---------------------------------------------------------------------------
// Kernel 1: QKV projections via bf16 MFMA. C = X @ W^T + b.
// 128x128 tile, BK=32, 4 waves (2x2 of 64x64), 16x16x32 MFMA.
// 2-phase double-buffered, one barrier per K-iter. A (x fp32) converted
// in-staging with v_cvt_pk_bf16_f32 (8 instr/iter vs ~56); B via GLL16.
// Grid is N-MAJOR (4,128,3): 4 consecutive blocks share the A row-panel
// -> L2/L3 locality on the 4x X re-read.
// Epilogue: z=0 Q (scaled 0.125*log2e); z=1 K; z=2 V transposed (B,H,DH,S).
// ---------------------------------------------------------------------------
__global__ __launch_bounds__(256) void qkv_gemm_kernel(
    const float* __restrict__ xq, const float* __restrict__ xk, const float* __restrict__ xv,
    const ush* __restrict__ wbf,
    const float* __restrict__ bq, const float* __restrict__ bk, const float* __restrict__ bv,
    ush* __restrict__ Qb, ush* __restrict__ Kb, ush* __restrict__ VT)
{
    __shared__ ush As[2][4096];   // 8 chunks x 512 shorts = 8 KB per buffer
    __shared__ ush Bs[2][4096];

    const int z = blockIdx.z;
    const float* X    = (z == 0) ? xq : (z == 1) ? xk : xv;
    const ush*   W    = wbf + z * 262144;
    const float* bias = (z == 0) ? bq : (z == 1) ? bk : bv;

    const int t = threadIdx.x;
    const int w = t >> 6, l = t & 63;
    const int l15 = l & 15, g = l >> 4;
    const int m0 = blockIdx.y * 128, n0 = blockIdx.x * 128;   // n-major grid
    const int wm = (w & 1) << 6, wn = (w >> 1) << 6;

    const int srow = l >> 2;                                   // row within chunk
    const int sg   = (l & 3) ^ ((srow + (srow >> 2)) & 3);     // staged k-group
    const int fsw  = (g ^ ((l15 + (l15 >> 2)) & 3)) << 3;      // frag-read swizzle (shorts)
    const int c0   = w * 2;                                    // this wave's chunks

    f32x4 acc[4][4];
    #pragma unroll
    for (int i = 0; i < 4; ++i)
        #pragma unroll
        for (int j = 0; j < 4; ++j) acc[i][j] = (f32x4)(0.0f);

    // pack 4 float4 (16 floats) -> 2 uint4 of bf16 via cvt_pk
    auto packA = [&](const float4& a0, const float4& a1, const float4& a2,
                     const float4& a3, uint4& u0, uint4& u1) {
        u0.x = cvt_pk_bf16(a0.x, a0.y);
        u0.y = cvt_pk_bf16(a0.z, a0.w);
        u0.z = cvt_pk_bf16(a1.x, a1.y);
        u0.w = cvt_pk_bf16(a1.z, a1.w);
        u1.x = cvt_pk_bf16(a2.x, a2.y);
        u1.y = cvt_pk_bf16(a2.z, a2.w);
        u1.z = cvt_pk_bf16(a3.x, a3.y);
        u1.w = cvt_pk_bf16(a3.z, a3.w);
    };

    // ---- prologue: stage kt=0 into buffer 0 ----
    {
        const size_t ar0 = (size_t)(m0 + c0 * 16 + srow) * 512 + sg * 8;
        const size_t ar1 = (size_t)(m0 + (c0 + 1) * 16 + srow) * 512 + sg * 8;
        const float4 a0 = *(const float4*)&X[ar0];
        const float4 a1 = *(const float4*)&X[ar0 + 4];
        const float4 a2 = *(const float4*)&X[ar1];
        const float4 a3 = *(const float4*)&X[ar1 + 4];
        GLL16(&W[(size_t)(n0 + c0 * 16 + srow) * 512 + sg * 8], &Bs[0][c0 * 512 + l * 8]);
        GLL16(&W[(size_t)(n0 + (c0 + 1) * 16 + srow) * 512 + sg * 8], &Bs[0][(c0 + 1) * 512 + l * 8]);
        uint4 u0, u1;
        packA(a0, a1, a2, a3, u0, u1);
        *(uint4*)&As[0][c0 * 512 + l * 8] = u0;
        *(uint4*)&As[0][(c0 + 1) * 512 + l * 8] = u1;
        __syncthreads();
    }

    for (int ki = 0; ki < 16; ++ki) {
        const int buf = ki & 1;
        const int ktn = (ki + 1) * 32;   // next tile's k offset
        float4 a0, a1, a2, a3;
        if (ki < 15) {
            // issue next tile's loads FIRST (span this tile's MFMAs)
            const size_t ar0 = (size_t)(m0 + c0 * 16 + srow) * 512 + ktn + sg * 8;
            const size_t ar1 = (size_t)(m0 + (c0 + 1) * 16 + srow) * 512 + ktn + sg * 8;
            a0 = *(const float4*)&X[ar0];
            a1 = *(const float4*)&X[ar0 + 4];
            a2 = *(const float4*)&X[ar1];
            a3 = *(const float4*)&X[ar1 + 4];
            GLL16(&W[(size_t)(n0 + c0 * 16 + srow) * 512 + ktn + sg * 8], &Bs[buf ^ 1][c0 * 512 + l * 8]);
            GLL16(&W[(size_t)(n0 + (c0 + 1) * 16 + srow) * 512 + ktn + sg * 8], &Bs[buf ^ 1][(c0 + 1) * 512 + l * 8]);
        }

        // compute current tile
        bf16x8 af[4], bfr[4];
        #pragma unroll
        for (int mi = 0; mi < 4; ++mi)
            af[mi] = *(const bf16x8*)&As[buf][(((w & 1) << 2) + mi) * 512 + l15 * 32 + fsw];
        #pragma unroll
        for (int ni = 0; ni < 4; ++ni)
            bfr[ni] = *(const bf16x8*)&Bs[buf][(((w >> 1) << 2) + ni) * 512 + l15 * 32 + fsw];
        #pragma unroll
        for (int mi = 0; mi < 4; ++mi)
            #pragma unroll
            for (int ni = 0; ni < 4; ++ni)
                acc[mi][ni] = __builtin_amdgcn_mfma_f32_16x16x32_bf16(af[mi], bfr[ni], acc[mi][ni], 0, 0, 0);

        if (ki < 15) {
            uint4 u0, u1;
            packA(a0, a1, a2, a3, u0, u1);
            *(uint4*)&As[buf ^ 1][c0 * 512 + l * 8] = u0;
            *(uint4*)&As[buf ^ 1][(c0 + 1) * 512 + l * 8] = u1;
        }
        __syncthreads();   // drains vmcnt (GLL16) + lgkm; protects buf reuse
    }

    const float qscale = (z == 0) ? 0.18033688011112042f : 1.0f;   // 0.125*log2(e)
    float bnv[4];
    #pragma unroll
    for (int ni = 0; ni < 4; ++ni) bnv[ni] = bias[n0 + wn + ni * 16 + l15];

    if (z < 2) {
        ush* O = (z == 0) ? Qb : Kb;
        #pragma unroll
        for (int mi = 0; mi < 4; ++mi) {
            #pragma unroll
            for (int ni = 0; ni < 4; ++ni) {
                const int n = n0 + wn + ni * 16 + l15;
                const int hh = n >> 6, dh = n & 63;
                const int mb = m0 + wm + mi * 16 + (g << 2);
                const int bi = mb >> 11, s = mb & (NS - 1);
                const size_t base = ((size_t)(bi * 8 + hh) * 2048 + s) * 64 + dh;
                const unsigned u01 = cvt_pk_bf16((acc[mi][ni][0] + bnv[ni]) * qscale,
                                                 (acc[mi][ni][1] + bnv[ni]) * qscale);
                const unsigned u23 = cvt_pk_bf16((acc[mi][ni][2] + bnv[ni]) * qscale,
                                                 (acc[mi][ni][3] + bnv[ni]) * qscale);
                O[base]           = (ush)u01;
                O[base + 64]      = (ush)(u01 >> 16);
                O[base + 128]     = (ush)u23;
                O[base + 192]     = (ush)(u23 >> 16);
            }
        }
    } else {
        #pragma unroll
        for (int mi = 0; mi < 4; ++mi) {
            #pragma unroll
            for (int ni = 0; ni < 4; ++ni) {
                const int n = n0 + wn + ni * 16 + l15;
                const int hh = n >> 6, dh = n & 63;
                const int mb = m0 + wm + mi * 16 + (g << 2);
                const int bi = mb >> 11, s = mb & (NS - 1);
                uint2 pk;
                pk.x = cvt_pk_bf16(acc[mi][ni][0] + bnv[ni], acc[mi][ni][1] + bnv[ni]);
                pk.y = cvt_pk_bf16(acc[mi][ni][2] + bnv[ni], acc[mi][ni][3] + bnv[ni]);
                *(uint2*)&VT[((size_t)(bi * 8 + hh) * 64 + dh) * 2048 + s] = pk;
            }
        }
    }
}

// ---------------------------------------------------------------------------
// Kernel 2: flash attention, S^T formulation, 2 Q-tiles per block, 1-tile
// software pipeline (as R5) + LPT BATCH SCHEDULING: every block argsorts
// the 8 lens (descending, stable) and takes b = order[id>>7], so the
// longest batches are dispatched first and the tail is the shortest ->
// near-flat makespan across CUs (fixes the 16.5% occupancy of R5).
// Correctness is dispatch-order-independent (pure permutation of b).
// ---------------------------------------------------------------------------
__global__ __launch_bounds__(256) void attn_kernel(
    ush* __restrict__ Qb, const ush* __restrict__ Kb,
    const ush* __restrict__ VT, const int* __restrict__ lens,
    ush* __restrict__ ctx_lo)
{
    __shared__ ush Ps[128 * 72];    // [q_local][key] two q-tiles, wave-private rows
    __shared__ ush Vt[2 * 4624];    // double-buffered [dv][key]

    const int tid = threadIdx.x;
    const int w = tid >> 6, l = tid & 63;
    const int l15 = l & 15, g = l >> 4;

    const int id = blockIdx.x;

    // LPT: slot id>>7 takes the (id>>7)-th longest batch
    int Ls[8];
    #pragma unroll
    for (int j = 0; j < 8; ++j) Ls[j] = lens[j];
    const int slot = id >> 7;
    int b = 0;
    #pragma unroll
    for (int bb = 0; bb < 8; ++bb) {
        int r = 0;
        #pragma unroll
        for (int j = 0; j < 8; ++j)
            r += (Ls[j] > Ls[bb]) || (Ls[j] == Ls[bb] && j < bb);
        if (r == slot) b = bb;
    }
    const int h = id & 7, qt = (id >> 3) & 15;
    const int L = Ls[b];
    const int q0 = qt << 7;
    const size_t bh = ((size_t)b * 8 + h) * 2048;

    // Q B-fragments, two q-tiles (rows q0+w*16.. and q0+64+w*16..)
    const ush* qptr = Qb + (bh + q0 + w * 16 + l15) * 64 + g * 8;
    const bf16x8 qfa0 = *(const bf16x8*)(qptr);
    const bf16x8 qfa1 = *(const bf16x8*)(qptr + 32);
    const bf16x8 qfb0 = *(const bf16x8*)(qptr + 64 * 64);
    const bf16x8 qfb1 = *(const bf16x8*)(qptr + 64 * 64 + 32);

    const ush* kbase = Kb + (bh + l15) * 64 + g * 8;

    // V^T staging: thread owns dv row, 16-key segment
    const int dv = tid >> 2, seg = (tid & 3) << 4;
    const ush* vbase = VT + bh * 64 + (size_t)dv * 2048 + seg;
    const int vt_off = dv * 72 + ((dv >> 4) << 3) + seg;

    // Ps pointers (wave-private rows; +64*72 for q-tile b)
    ush* psw_a = &Ps[(w * 16 + l15) * 72 + (g << 2)];
    const ush* pp_a = &Ps[(w * 16 + l15) * 72 + g * 8];
    ush* psw_b = psw_a + 64 * 72;
    const ush* pp_b = pp_a + 64 * 72;

    // constant ones B-fragment for the l-MFMA (bf16 1.0 = 0x3F80)
    bf16x8 ones;
    #pragma unroll
    for (int j = 0; j < 8; ++j) ones[j] = (short)0x3F80;

    f32x4 oa[4], ob[4];
    f32x4 ola = (f32x4)(0.0f), olb = (f32x4)(0.0f);
    #pragma unroll
    for (int i = 0; i < 4; ++i) { oa[i] = (f32x4)(0.0f); ob[i] = (f32x4)(0.0f); }

    f32x4 spa[4], spb[4];       // in-flight scores, both q-tiles
    const int T = (L + 63) >> 6;

    // ---- prologue: tile 0 scores + V0 staging ----
    {
        const uint4 v0 = *(const uint4*)(vbase);
        const uint4 v1 = *(const uint4*)(vbase + 8);
        #pragma unroll
        for (int st = 0; st < 4; ++st) { spa[st] = (f32x4)(0.0f); spb[st] = (f32x4)(0.0f); }
        __builtin_amdgcn_s_setprio(1);
        #pragma unroll
        for (int st = 0; st < 4; ++st) {
            const bf16x8 kf0 = *(const bf16x8*)(kbase + st * 1024);
            const bf16x8 kf1 = *(const bf16x8*)(kbase + st * 1024 + 32);
            spa[st] = __builtin_amdgcn_mfma_f32_16x16x32_bf16(kf0, qfa0, spa[st], 0, 0, 0);
            spa[st] = __builtin_amdgcn_mfma_f32_16x16x32_bf16(kf1, qfa1, spa[st], 0, 0, 0);
            spb[st] = __builtin_amdgcn_mfma_f32_16x16x32_bf16(kf0, qfb0, spb[st], 0, 0, 0);
            spb[st] = __builtin_amdgcn_mfma_f32_16x16x32_bf16(kf1, qfb1, spb[st], 0, 0, 0);
        }
        __builtin_amdgcn_s_setprio(0);
        ush* dst = &Vt[vt_off];
        *(uint4*)dst = v0;
        *(uint4*)(dst + 8) = v1;
        __syncthreads();
    }

    // finish a completed tile (both q-tiles, shared V-fragment reads)
    auto finish = [&](const ush* vb, bool masked, int kb0) {
        uint2 pka[4], pkb[4];
        #pragma unroll
        for (int st = 0; st < 4; ++st) {
            float pa[4], pb[4];
            #pragma unroll
            for (int r = 0; r < 4; ++r) {
                float ea = EXP2F(spa[st][r]);
                float eb = EXP2F(spb[st][r]);
                if (masked) {
                    const int key = kb0 + st * 16 + (g << 2) + r;
                    ea = (key < L) ? ea : 0.0f;
                    eb = (key < L) ? eb : 0.0f;
                }
                pa[r] = ea; pb[r] = eb;
            }
            pka[st].x = cvt_pk_bf16(pa[0], pa[1]);
            pka[st].y = cvt_pk_bf16(pa[2], pa[3]);
            pkb[st].x = cvt_pk_bf16(pb[0], pb[1]);
            pkb[st].y = cvt_pk_bf16(pb[2], pb[3]);
        }
        #pragma unroll
        for (int st = 0; st < 4; ++st) {
            *(uint2*)(psw_a + st * 16) = pka[st];
            *(uint2*)(psw_b + st * 16) = pkb[st];
        }
        const bf16x8 pfa0 = *(const bf16x8*)(pp_a);
        const bf16x8 pfa1 = *(const bf16x8*)(pp_a + 32);
        const bf16x8 pfb0 = *(const bf16x8*)(pp_b);
        const bf16x8 pfb1 = *(const bf16x8*)(pp_b + 32);
        __builtin_amdgcn_s_setprio(1);
        ola = __builtin_amdgcn_mfma_f32_16x16x32_bf16(pfa0, ones, ola, 0, 0, 0);
        ola = __builtin_amdgcn_mfma_f32_16x16x32_bf16(pfa1, ones, ola, 0, 0, 0);
        olb = __builtin_amdgcn_mfma_f32_16x16x32_bf16(pfb0, ones, olb, 0, 0, 0);
        olb = __builtin_amdgcn_mfma_f32_16x16x32_bf16(pfb1, ones, olb, 0, 0, 0);
        #pragma unroll
        for (int st2 = 0; st2 < 4; ++st2) {
            const ush* vp = vb + (st2 * 16 + l15) * 72 + (st2 << 3) + g * 8;
            const bf16x8 vf0 = *(const bf16x8*)(vp);
            const bf16x8 vf1 = *(const bf16x8*)(vp + 32);
            oa[st2] = __builtin_amdgcn_mfma_f32_16x16x32_bf16(pfa0, vf0, oa[st2], 0, 0, 0);
            oa[st2] = __builtin_amdgcn_mfma_f32_16x16x32_bf16(pfa1, vf1, oa[st2], 0, 0, 0);
            ob[st2] = __builtin_amdgcn_mfma_f32_16x16x32_bf16(pfb0, vf0, ob[st2], 0, 0, 0);
            ob[st2] = __builtin_amdgcn_mfma_f32_16x16x32_bf16(pfb1, vf1, ob[st2], 0, 0, 0);
        }
        __builtin_amdgcn_s_setprio(0);
    };

    // ---- main loop: tiles 1..T-1 ----
    for (int t = 1; t < T; ++t) {
        const int k0 = t << 6;
        // early-issue K then V for tile t
        bf16x8 kf[8];
        const ush* kp = kbase + (size_t)k0 * 64;
        #pragma unroll
        for (int st = 0; st < 4; ++st) {
            kf[2 * st]     = *(const bf16x8*)(kp + st * 1024);
            kf[2 * st + 1] = *(const bf16x8*)(kp + st * 1024 + 32);
        }
        const uint4 nv0 = *(const uint4*)(vbase + k0);
        const uint4 nv1 = *(const uint4*)(vbase + k0 + 8);

        // finish tile t-1 (always FULL)
        finish(&Vt[((t & 1) ^ 1) * 4624], false, 0);

        // S^T MFMA tile t, both q-tiles
        #pragma unroll
        for (int st = 0; st < 4; ++st) { spa[st] = (f32x4)(0.0f); spb[st] = (f32x4)(0.0f); }
        __builtin_amdgcn_s_setprio(1);
        #pragma unroll
        for (int st = 0; st < 4; ++st) {
            spa[st] = __builtin_amdgcn_mfma_f32_16x16x32_bf16(kf[2 * st], qfa0, spa[st], 0, 0, 0);
            spa[st] = __builtin_amdgcn_mfma_f32_16x16x32_bf16(kf[2 * st + 1], qfa1, spa[st], 0, 0, 0);
            spb[st] = __builtin_amdgcn_mfma_f32_16x16x32_bf16(kf[2 * st], qfb0, spb[st], 0, 0, 0);
            spb[st] = __builtin_amdgcn_mfma_f32_16x16x32_bf16(kf[2 * st + 1], qfb1, spb[st], 0, 0, 0);
        }
        __builtin_amdgcn_s_setprio(0);

        // stage V tile t
        ush* dst = &Vt[(t & 1) * 4624 + vt_off];
        *(uint4*)dst = nv0;
        *(uint4*)(dst + 8) = nv1;
        __syncthreads();
    }

    // ---- epilogue: finish tile T-1 (possibly partial) ----
    finish(&Vt[((T - 1) & 1) * 4624], true, (T - 1) << 6);

    #pragma unroll
    for (int r = 0; r < 4; ++r) {
        const float inva = 1.0f / ola[r];
        const float invb = 1.0f / olb[r];
        const size_t rowa = bh + q0 + w * 16 + (g << 2) + r;
        const size_t rowb = rowa + 64;
        #pragma unroll
        for (int st2 = 0; st2 < 4; ++st2) {
            const float va = oa[st2][r] * inva;
            const ush ha = f2bf_rne(va);
            Qb[rowa * 64 + st2 * 16 + l15] = ha;
            ctx_lo[rowa * 64 + st2 * 16 + l15] = f2bf_rne(va - bf2f(ha));
            const float vbv = ob[st2][r] * invb;
            const ush hb = f2bf_rne(vbv);
            Qb[rowb * 64 + st2 * 16 + l15] = hb;
            ctx_lo[rowb * 64 + st2 * 16 + l15] = f2bf_rne(vbv - bf2f(hb));
        }
    }
}

// ---------------------------------------------------------------------------
// Kernel 3: out = ctx @ Wo^T + bo, 3-term split bf16 MFMA.
// 8-WAVE (512 threads): wave grid 2(m)x4(n), wave tile 64x32, acc 4x2.
// Same 64 KB LDS (2 blocks/CU) but 4 waves/SIMD instead of 2 -> double
// the latency hiding on the ds_read->48-MFMA chain and GLL16 drains.
// 2-phase double-buffered; grid N-MAJOR (4,128).
// ---------------------------------------------------------------------------
__global__ __launch_bounds__(512) void out_gemm_kernel(
    const ush* __restrict__ ctx_hi, const ush* __restrict__ ctx_lo,
    const ush* __restrict__ wo_hi, const ush* __restrict__ wo_lo,
    const float* __restrict__ bo, float* __restrict__ out)
{
    __shared__ ush Ah[2][4096], Al[2][4096], Bh[2][4096], Bl[2][4096];

    const int t = threadIdx.x;
    const int w = t >> 6, l = t & 63;
    const int l15 = l & 15, g = l >> 4;
    const int m0 = blockIdx.y * 128, n0 = blockIdx.x * 128;   // n-major grid
    const int wm = (w & 1) << 6, wn = (w >> 1) << 5;

    const int srow = l >> 2;
    const int sg   = (l & 3) ^ ((srow + (srow >> 2)) & 3);
    const int fsw  = (g ^ ((l15 + (l15 >> 2)) & 3)) << 3;
    const int c0   = w;                                       // 1 chunk per wave

    f32x4 acc[4][2];
    #pragma unroll
    for (int i = 0; i < 4; ++i)
        #pragma unroll
        for (int j = 0; j < 2; ++j) acc[i][j] = (f32x4)(0.0f);

    // stage one K-tile into buffer `bf` (each wave: its chunk, 4 arrays)
    auto stage = [&](int bf, int kt) {
        const int c = c0;
        const int m = m0 + c * 16 + srow;
        const int k = kt + sg * 8;
        const size_t ga = ((size_t)((m >> 11) * 8 + (k >> 6)) * 2048 + (m & (NS - 1))) * 64 + (k & 63);
        GLL16(&ctx_hi[ga], &Ah[bf][c * 512 + l * 8]);
        GLL16(&ctx_lo[ga], &Al[bf][c * 512 + l * 8]);
        const size_t gb = (size_t)(n0 + c * 16 + srow) * 512 + kt + sg * 8;
        GLL16(&wo_hi[gb], &Bh[bf][c * 512 + l * 8]);
        GLL16(&wo_lo[gb], &Bl[bf][c * 512 + l * 8]);
    };

    stage(0, 0);
    __syncthreads();

    for (int ki = 0; ki < 16; ++ki) {
        const int buf = ki & 1;
        if (ki < 15) stage(buf ^ 1, (ki + 1) * 32);

        bf16x8 ah[4], al[4], bh4[2], bl4[2];
        #pragma unroll
        for (int mi = 0; mi < 4; ++mi) {
            const int off = (((w & 1) << 2) + mi) * 512 + l15 * 32 + fsw;
            ah[mi] = *(const bf16x8*)&Ah[buf][off];
            al[mi] = *(const bf16x8*)&Al[buf][off];
        }
        #pragma unroll
        for (int ni = 0; ni < 2; ++ni) {
            const int off = (((w >> 1) << 1) + ni) * 512 + l15 * 32 + fsw;
            bh4[ni] = *(const bf16x8*)&Bh[buf][off];
            bl4[ni] = *(const bf16x8*)&Bl[buf][off];
        }
        #pragma unroll
        for (int mi = 0; mi < 4; ++mi)
            #pragma unroll
            for (int ni = 0; ni < 2; ++ni) {
                acc[mi][ni] = __builtin_amdgcn_mfma_f32_16x16x32_bf16(ah[mi], bh4[ni], acc[mi][ni], 0, 0, 0);
                acc[mi][ni] = __builtin_amdgcn_mfma_f32_16x16x32_bf16(al[mi], bh4[ni], acc[mi][ni], 0, 0, 0);
                acc[mi][ni] = __builtin_amdgcn_mfma_f32_16x16x32_bf16(ah[mi], bl4[ni], acc[mi][ni], 0, 0, 0);
            }
        __syncthreads();   // drains this iter's GLL16s; protects buf reuse
    }

    float bov[2];
    #pragma unroll
    for (int ni = 0; ni < 2; ++ni) bov[ni] = bo[n0 + wn + ni * 16 + l15];

    #pragma unroll
    for (int mi = 0; mi < 4; ++mi)
        #pragma unroll
        for (int ni = 0; ni < 2; ++ni) {
            const int n = n0 + wn + ni * 16 + l15;
            #pragma unroll
            for (int r = 0; r < 4; ++r) {
                const int m = m0 + wm + mi * 16 + (g << 2) + r;
                out[(size_t)m * 512 + n] = acc[mi][ni][r] + bov[ni];
            }
        }
}

// ---------------------------------------------------------------------------
extern "C" void kernel_launch(void* const* d_in, const int* in_sizes, int n_in,
                              void* d_out, int out_size, void* d_ws, size_t ws_size,
                              hipStream_t stream)
{
    const float* xq   = (const float*)d_in[0];
    const float* xk   = (const float*)d_in[1];
    const float* xv   = (const float*)d_in[2];
    const float* Wq   = (const float*)d_in[3];
    const float* bq   = (const float*)d_in[4];
    const float* Wk   = (const float*)d_in[5];
    const float* bk   = (const float*)d_in[6];
    const float* Wv   = (const float*)d_in[7];
    const float* bv   = (const float*)d_in[8];
    const float* Wo   = (const float*)d_in[9];
    const float* bo   = (const float*)d_in[10];
    const int*   lens = (const int*)d_in[11];
    float* out = (float*)d_out;

    const size_t elems = (size_t)NB * NHH * NS * NDH;   // 8.39M
    ush* Qb     = (ush*)d_ws;          // bf16 Q (pre-scaled); later ctx_hi in place
    ush* Kb     = Qb + elems;
    ush* VT     = Kb + elems;          // V transposed (B,H,DH,S)
    ush* ctx_lo = VT + elems;
    ush* wbf    = ctx_lo + elems;      // Wq,Wk,Wv bf16 (3*262144)
    ush* wo_hi  = wbf + 3 * 262144;
    ush* wo_lo  = wo_hi + 262144;
    // total: 4*8.39M + 5*262144 shorts = 69.7 MB (< 100.7 MB proven in R1)

    const dim3 blk(256);
    conv_w_kernel<<<dim3(256, 4), blk, 0, stream>>>(Wq, Wk, Wv, Wo, wbf, wo_hi, wo_lo);
    qkv_gemm_kernel<<<dim3(4, 128, 3), blk, 0, stream>>>(
        xq, xk, xv, wbf, bq, bk, bv, Qb, Kb, VT);
    attn_kernel<<<dim3(NB * NHH * (NS / 128)), blk, 0, stream>>>(Qb, Kb, VT, lens, ctx_lo);
    out_gemm_kernel<<<dim3(4, 128), dim3(512), 0, stream>>>(Qb, ctx_lo, wo_hi, wo_lo, bo, out);
}

// Round 8
// 299.472 us; speedup vs baseline: 1.4796x; 1.0085x over previous
//
#include <hip/hip_runtime.h>
#include <math.h>

#define NB 8
#define NS 2048
#define ND 512
#define NHH 8
#define NDH 64

typedef __attribute__((ext_vector_type(4))) float f32x4;
typedef __attribute__((ext_vector_type(8))) short bf16x8;
typedef unsigned short ush;

__device__ inline ush f2bf_rne(float f) {
    unsigned u = __float_as_uint(f);
    unsigned r = u + 0x7FFFu + ((u >> 16) & 1u);
    return (ush)(r >> 16);
}
__device__ inline float bf2f(ush h) { return __uint_as_float(((unsigned)h) << 16); }

// packed f32x2 -> bf16x2 (RNE), single VALU instruction; low half = first arg
__device__ inline unsigned cvt_pk_bf16(float lo, float hi) {
    unsigned r;
    asm("v_cvt_pk_bf16_f32 %0, %1, %2" : "=v"(r) : "v"(lo), "v"(hi));
    return r;
}

#if defined(__has_builtin)
#if __has_builtin(__builtin_amdgcn_exp2f)
#define EXP2F(x) __builtin_amdgcn_exp2f(x)
#else
#define EXP2F(x) exp2f(x)
#endif
#else
#define EXP2F(x) exp2f(x)
#endif

// async global->LDS, 16B per lane (global_load_lds_dwordx4)
#define GLL16(gp, lp) __builtin_amdgcn_global_load_lds( \
    (const __attribute__((address_space(1))) unsigned int*)(gp), \
    (__attribute__((address_space(3))) unsigned int*)(lp), 16, 0, 0)

// ---------------------------------------------------------------------------
// Kernel 0a: weight conversion. y<3: Wq/Wk/Wv -> bf16. y==3: Wo -> hi/lo.
// ---------------------------------------------------------------------------
__global__ __launch_bounds__(256) void conv_w_kernel(
    const float* __restrict__ Wq, const float* __restrict__ Wk,
    const float* __restrict__ Wv, const float* __restrict__ Wo,
    ush* __restrict__ wbf, ush* __restrict__ wo_hi, ush* __restrict__ wo_lo)
{
    const int y = blockIdx.y;
    const int i = (blockIdx.x * 256 + threadIdx.x) * 4;
    if (y < 3) {
        const float* src = (y == 0) ? Wq : (y == 1) ? Wk : Wv;
        const float4 v = *(const float4*)&src[i];
        ushort4 o;
        o.x = f2bf_rne(v.x); o.y = f2bf_rne(v.y);
        o.z = f2bf_rne(v.z); o.w = f2bf_rne(v.w);
        *(ushort4*)&wbf[y * 262144 + i] = o;
    } else {
        const float4 v = *(const float4*)&Wo[i];
        ushort4 hi, lo;
        hi.x = f2bf_rne(v.x); lo.x = f2bf_rne(v.x - bf2f(hi.x));
        hi.y = f2bf_rne(v.y); lo.y = f2bf_rne(v.y - bf2f(hi.y));
        hi.z = f2bf_rne(v.z); lo.z = f2bf_rne(v.z - bf2f(hi.z));
        hi.w = f2bf_rne(v.w); lo.w = f2bf_rne(v.w - bf2f(hi.w));
        *(ushort4*)&wo_hi[i] = hi;
        *(ushort4*)&wo_lo[i] = lo;
    }
}

// ---------------------------------------------------------------------------
// Kernel 0b: X -> bf16 streaming convert (RNE, identical rounding to the
// old in-kernel staging convert). Each y-slice converts B*S*D = 8.39M
// floats -> grid.x = 8.39M / (256*4) = 8192 blocks (R7 crash: was 16384).
// Destinations alias out (xq,xk) and ctx_lo (xv) -- stream-ordered reuse.
// ---------------------------------------------------------------------------
__global__ __launch_bounds__(256) void conv_x_kernel(
    const float* __restrict__ xq, const float* __restrict__ xk,
    const float* __restrict__ xv,
    ush* __restrict__ xqb, ush* __restrict__ xkb, ush* __restrict__ xvb)
{
    const int y = blockIdx.y;
    const float* src = (y == 0) ? xq : (y == 1) ? xk : xv;
    ush* dst = (y == 0) ? xqb : (y == 1) ? xkb : xvb;
    const size_t i = ((size_t)blockIdx.x * 256 + threadIdx.x) * 4;
    const float4 v = *(const float4*)&src[i];
    uint2 p;
    p.x = cvt_pk_bf16(v.x, v.y);
    p.y = cvt_pk_bf16(v.z, v.w);
    *(uint2*)&dst[i] = p;
}

// ---------------------------------------------------------------------------
// Kernel 1: QKV projections via bf16 MFMA. C = Xbf @ W^T + b.
// 128x128 tile, BK=32, 4 waves, 16x16x32 MFMA. ALL-GLL16 staging (A and B
// both bf16 async direct-to-LDS; zero VALU staging work in the K-loop).
// 2-phase double-buffered, one barrier/iter.
// XCD-AWARE GRID (linear j): xcd=j&7 owns m-panels {xcd, xcd+8, ...};
// n=(j>>3)&3; the 4 n-blocks of a panel have ids = mod 8 -> same XCD L2,
// so the 4x A-panel re-read hits L2 instead of HBM.
// Epilogue: z=0 Q (scaled 0.125*log2e); z=1 K; z=2 V transposed (B,H,DH,S).
// ---------------------------------------------------------------------------
__global__ __launch_bounds__(256) void qkv_gemm_kernel(
    const ush* __restrict__ xqb, const ush* __restrict__ xkb, const ush* __restrict__ xvb,
    const ush* __restrict__ wbf,
    const float* __restrict__ bq, const float* __restrict__ bk, const float* __restrict__ bv,
    ush* __restrict__ Qb, ush* __restrict__ Kb, ush* __restrict__ VT)
{
    __shared__ ush As[2][4096];   // 8 chunks x 512 shorts = 8 KB per buffer
    __shared__ ush Bs[2][4096];

    const int z = blockIdx.z;
    const ush*   XA   = (z == 0) ? xqb : (z == 1) ? xkb : xvb;
    const ush*   W    = wbf + z * 262144;
    const float* bias = (z == 0) ? bq : (z == 1) ? bk : bv;

    const int t = threadIdx.x;
    const int w = t >> 6, l = t & 63;
    const int l15 = l & 15, g = l >> 4;

    // XCD-aware block mapping
    const int j = blockIdx.x;
    const int m0 = ((j & 7) + (j >> 5) * 8) * 128;
    const int n0 = ((j >> 3) & 3) * 128;
    const int wm = (w & 1) << 6, wn = (w >> 1) << 6;

    const int srow = l >> 2;                                   // row within chunk
    const int sg   = (l & 3) ^ ((srow + (srow >> 2)) & 3);     // staged k-group
    const int fsw  = (g ^ ((l15 + (l15 >> 2)) & 3)) << 3;      // frag-read swizzle (shorts)
    const int c0   = w * 2;                                    // this wave's chunks

    f32x4 acc[4][4];
    #pragma unroll
    for (int i = 0; i < 4; ++i)
        #pragma unroll
        for (int jj = 0; jj < 4; ++jj) acc[i][jj] = (f32x4)(0.0f);

    auto stage = [&](int bf, int kt) {
        GLL16(&XA[(size_t)(m0 + c0 * 16 + srow) * 512 + kt + sg * 8], &As[bf][c0 * 512 + l * 8]);
        GLL16(&XA[(size_t)(m0 + (c0 + 1) * 16 + srow) * 512 + kt + sg * 8], &As[bf][(c0 + 1) * 512 + l * 8]);
        GLL16(&W[(size_t)(n0 + c0 * 16 + srow) * 512 + kt + sg * 8], &Bs[bf][c0 * 512 + l * 8]);
        GLL16(&W[(size_t)(n0 + (c0 + 1) * 16 + srow) * 512 + kt + sg * 8], &Bs[bf][(c0 + 1) * 512 + l * 8]);
    };

    stage(0, 0);
    __syncthreads();

    for (int ki = 0; ki < 16; ++ki) {
        const int buf = ki & 1;
        if (ki < 15) stage(buf ^ 1, (ki + 1) * 32);

        bf16x8 af[4], bfr[4];
        #pragma unroll
        for (int mi = 0; mi < 4; ++mi)
            af[mi] = *(const bf16x8*)&As[buf][(((w & 1) << 2) + mi) * 512 + l15 * 32 + fsw];
        #pragma unroll
        for (int ni = 0; ni < 4; ++ni)
            bfr[ni] = *(const bf16x8*)&Bs[buf][(((w >> 1) << 2) + ni) * 512 + l15 * 32 + fsw];
        #pragma unroll
        for (int mi = 0; mi < 4; ++mi)
            #pragma unroll
            for (int ni = 0; ni < 4; ++ni)
                acc[mi][ni] = __builtin_amdgcn_mfma_f32_16x16x32_bf16(af[mi], bfr[ni], acc[mi][ni], 0, 0, 0);

        __syncthreads();   // drains vmcnt (GLL16s); protects buf reuse
    }

    const float qscale = (z == 0) ? 0.18033688011112042f : 1.0f;   // 0.125*log2(e)
    float bnv[4];
    #pragma unroll
    for (int ni = 0; ni < 4; ++ni) bnv[ni] = bias[n0 + wn + ni * 16 + l15];

    if (z < 2) {
        ush* O = (z == 0) ? Qb : Kb;
        #pragma unroll
        for (int mi = 0; mi < 4; ++mi) {
            #pragma unroll
            for (int ni = 0; ni < 4; ++ni) {
                const int n = n0 + wn + ni * 16 + l15;
                const int hh = n >> 6, dh = n & 63;
                const int mb = m0 + wm + mi * 16 + (g << 2);
                const int bi = mb >> 11, s = mb & (NS - 1);
                const size_t base = ((size_t)(bi * 8 + hh) * 2048 + s) * 64 + dh;
                const unsigned u01 = cvt_pk_bf16((acc[mi][ni][0] + bnv[ni]) * qscale,
                                                 (acc[mi][ni][1] + bnv[ni]) * qscale);
                const unsigned u23 = cvt_pk_bf16((acc[mi][ni][2] + bnv[ni]) * qscale,
                                                 (acc[mi][ni][3] + bnv[ni]) * qscale);
                O[base]           = (ush)u01;
                O[base + 64]      = (ush)(u01 >> 16);
                O[base + 128]     = (ush)u23;
                O[base + 192]     = (ush)(u23 >> 16);
            }
        }
    } else {
        #pragma unroll
        for (int mi = 0; mi < 4; ++mi) {
            #pragma unroll
            for (int ni = 0; ni < 4; ++ni) {
                const int n = n0 + wn + ni * 16 + l15;
                const int hh = n >> 6, dh = n & 63;
                const int mb = m0 + wm + mi * 16 + (g << 2);
                const int bi = mb >> 11, s = mb & (NS - 1);
                uint2 pk;
                pk.x = cvt_pk_bf16(acc[mi][ni][0] + bnv[ni], acc[mi][ni][1] + bnv[ni]);
                pk.y = cvt_pk_bf16(acc[mi][ni][2] + bnv[ni], acc[mi][ni][3] + bnv[ni]);
                *(uint2*)&VT[((size_t)(bi * 8 + hh) * 64 + dh) * 2048 + s] = pk;
            }
        }
    }
}

// ---------------------------------------------------------------------------
// Kernel 2: flash attention, S^T formulation, 2 Q-tiles per block, 1-tile
// software pipeline + LPT batch scheduling (argsort lens desc; longest
// batches dispatch first -> flat makespan). Unchanged from R6.
// ---------------------------------------------------------------------------
__global__ __launch_bounds__(256) void attn_kernel(
    ush* __restrict__ Qb, const ush* __restrict__ Kb,
    const ush* __restrict__ VT, const int* __restrict__ lens,
    ush* __restrict__ ctx_lo)
{
    __shared__ ush Ps[128 * 72];    // [q_local][key] two q-tiles, wave-private rows
    __shared__ ush Vt[2 * 4624];    // double-buffered [dv][key]

    const int tid = threadIdx.x;
    const int w = tid >> 6, l = tid & 63;
    const int l15 = l & 15, g = l >> 4;

    const int id = blockIdx.x;

    // LPT: slot id>>7 takes the (id>>7)-th longest batch
    int Ls[8];
    #pragma unroll
    for (int j = 0; j < 8; ++j) Ls[j] = lens[j];
    const int slot = id >> 7;
    int b = 0;
    #pragma unroll
    for (int bb = 0; bb < 8; ++bb) {
        int r = 0;
        #pragma unroll
        for (int j = 0; j < 8; ++j)
            r += (Ls[j] > Ls[bb]) || (Ls[j] == Ls[bb] && j < bb);
        if (r == slot) b = bb;
    }
    const int h = id & 7, qt = (id >> 3) & 15;
    const int L = Ls[b];
    const int q0 = qt << 7;
    const size_t bh = ((size_t)b * 8 + h) * 2048;

    // Q B-fragments, two q-tiles (rows q0+w*16.. and q0+64+w*16..)
    const ush* qptr = Qb + (bh + q0 + w * 16 + l15) * 64 + g * 8;
    const bf16x8 qfa0 = *(const bf16x8*)(qptr);
    const bf16x8 qfa1 = *(const bf16x8*)(qptr + 32);
    const bf16x8 qfb0 = *(const bf16x8*)(qptr + 64 * 64);
    const bf16x8 qfb1 = *(const bf16x8*)(qptr + 64 * 64 + 32);

    const ush* kbase = Kb + (bh + l15) * 64 + g * 8;

    // V^T staging: thread owns dv row, 16-key segment
    const int dv = tid >> 2, seg = (tid & 3) << 4;
    const ush* vbase = VT + bh * 64 + (size_t)dv * 2048 + seg;
    const int vt_off = dv * 72 + ((dv >> 4) << 3) + seg;

    // Ps pointers (wave-private rows; +64*72 for q-tile b)
    ush* psw_a = &Ps[(w * 16 + l15) * 72 + (g << 2)];
    const ush* pp_a = &Ps[(w * 16 + l15) * 72 + g * 8];
    ush* psw_b = psw_a + 64 * 72;
    const ush* pp_b = pp_a + 64 * 72;

    // constant ones B-fragment for the l-MFMA (bf16 1.0 = 0x3F80)
    bf16x8 ones;
    #pragma unroll
    for (int j = 0; j < 8; ++j) ones[j] = (short)0x3F80;

    f32x4 oa[4], ob[4];
    f32x4 ola = (f32x4)(0.0f), olb = (f32x4)(0.0f);
    #pragma unroll
    for (int i = 0; i < 4; ++i) { oa[i] = (f32x4)(0.0f); ob[i] = (f32x4)(0.0f); }

    f32x4 spa[4], spb[4];       // in-flight scores, both q-tiles
    const int T = (L + 63) >> 6;

    // ---- prologue: tile 0 scores + V0 staging ----
    {
        const uint4 v0 = *(const uint4*)(vbase);
        const uint4 v1 = *(const uint4*)(vbase + 8);
        #pragma unroll
        for (int st = 0; st < 4; ++st) { spa[st] = (f32x4)(0.0f); spb[st] = (f32x4)(0.0f); }
        __builtin_amdgcn_s_setprio(1);
        #pragma unroll
        for (int st = 0; st < 4; ++st) {
            const bf16x8 kf0 = *(const bf16x8*)(kbase + st * 1024);
            const bf16x8 kf1 = *(const bf16x8*)(kbase + st * 1024 + 32);
            spa[st] = __builtin_amdgcn_mfma_f32_16x16x32_bf16(kf0, qfa0, spa[st], 0, 0, 0);
            spa[st] = __builtin_amdgcn_mfma_f32_16x16x32_bf16(kf1, qfa1, spa[st], 0, 0, 0);
            spb[st] = __builtin_amdgcn_mfma_f32_16x16x32_bf16(kf0, qfb0, spb[st], 0, 0, 0);
            spb[st] = __builtin_amdgcn_mfma_f32_16x16x32_bf16(kf1, qfb1, spb[st], 0, 0, 0);
        }
        __builtin_amdgcn_s_setprio(0);
        ush* dst = &Vt[vt_off];
        *(uint4*)dst = v0;
        *(uint4*)(dst + 8) = v1;
        __syncthreads();
    }

    // finish a completed tile (both q-tiles, shared V-fragment reads)
    auto finish = [&](const ush* vb, bool masked, int kb0) {
        uint2 pka[4], pkb[4];
        #pragma unroll
        for (int st = 0; st < 4; ++st) {
            float pa[4], pb[4];
            #pragma unroll
            for (int r = 0; r < 4; ++r) {
                float ea = EXP2F(spa[st][r]);
                float eb = EXP2F(spb[st][r]);
                if (masked) {
                    const int key = kb0 + st * 16 + (g << 2) + r;
                    ea = (key < L) ? ea : 0.0f;
                    eb = (key < L) ? eb : 0.0f;
                }
                pa[r] = ea; pb[r] = eb;
            }
            pka[st].x = cvt_pk_bf16(pa[0], pa[1]);
            pka[st].y = cvt_pk_bf16(pa[2], pa[3]);
            pkb[st].x = cvt_pk_bf16(pb[0], pb[1]);
            pkb[st].y = cvt_pk_bf16(pb[2], pb[3]);
        }
        #pragma unroll
        for (int st = 0; st < 4; ++st) {
            *(uint2*)(psw_a + st * 16) = pka[st];
            *(uint2*)(psw_b + st * 16) = pkb[st];
        }
        const bf16x8 pfa0 = *(const bf16x8*)(pp_a);
        const bf16x8 pfa1 = *(const bf16x8*)(pp_a + 32);
        const bf16x8 pfb0 = *(const bf16x8*)(pp_b);
        const bf16x8 pfb1 = *(const bf16x8*)(pp_b + 32);
        __builtin_amdgcn_s_setprio(1);
        ola = __builtin_amdgcn_mfma_f32_16x16x32_bf16(pfa0, ones, ola, 0, 0, 0);
        ola = __builtin_amdgcn_mfma_f32_16x16x32_bf16(pfa1, ones, ola, 0, 0, 0);
        olb = __builtin_amdgcn_mfma_f32_16x16x32_bf16(pfb0, ones, olb, 0, 0, 0);
        olb = __builtin_amdgcn_mfma_f32_16x16x32_bf16(pfb1, ones, olb, 0, 0, 0);
        #pragma unroll
        for (int st2 = 0; st2 < 4; ++st2) {
            const ush* vp = vb + (st2 * 16 + l15) * 72 + (st2 << 3) + g * 8;
            const bf16x8 vf0 = *(const bf16x8*)(vp);
            const bf16x8 vf1 = *(const bf16x8*)(vp + 32);
            oa[st2] = __builtin_amdgcn_mfma_f32_16x16x32_bf16(pfa0, vf0, oa[st2], 0, 0, 0);
            oa[st2] = __builtin_amdgcn_mfma_f32_16x16x32_bf16(pfa1, vf1, oa[st2], 0, 0, 0);
            ob[st2] = __builtin_amdgcn_mfma_f32_16x16x32_bf16(pfb0, vf0, ob[st2], 0, 0, 0);
            ob[st2] = __builtin_amdgcn_mfma_f32_16x16x32_bf16(pfb1, vf1, ob[st2], 0, 0, 0);
        }
        __builtin_amdgcn_s_setprio(0);
    };

    // ---- main loop: tiles 1..T-1 ----
    for (int t = 1; t < T; ++t) {
        const int k0 = t << 6;
        // early-issue K then V for tile t
        bf16x8 kf[8];
        const ush* kp = kbase + (size_t)k0 * 64;
        #pragma unroll
        for (int st = 0; st < 4; ++st) {
            kf[2 * st]     = *(const bf16x8*)(kp + st * 1024);
            kf[2 * st + 1] = *(const bf16x8*)(kp + st * 1024 + 32);
        }
        const uint4 nv0 = *(const uint4*)(vbase + k0);
        const uint4 nv1 = *(const uint4*)(vbase + k0 + 8);

        // finish tile t-1 (always FULL)
        finish(&Vt[((t & 1) ^ 1) * 4624], false, 0);

        // S^T MFMA tile t, both q-tiles
        #pragma unroll
        for (int st = 0; st < 4; ++st) { spa[st] = (f32x4)(0.0f); spb[st] = (f32x4)(0.0f); }
        __builtin_amdgcn_s_setprio(1);
        #pragma unroll
        for (int st = 0; st < 4; ++st) {
            spa[st] = __builtin_amdgcn_mfma_f32_16x16x32_bf16(kf[2 * st], qfa0, spa[st], 0, 0, 0);
            spa[st] = __builtin_amdgcn_mfma_f32_16x16x32_bf16(kf[2 * st + 1], qfa1, spa[st], 0, 0, 0);
            spb[st] = __builtin_amdgcn_mfma_f32_16x16x32_bf16(kf[2 * st], qfb0, spb[st], 0, 0, 0);
            spb[st] = __builtin_amdgcn_mfma_f32_16x16x32_bf16(kf[2 * st + 1], qfb1, spb[st], 0, 0, 0);
        }
        __builtin_amdgcn_s_setprio(0);

        // stage V tile t
        ush* dst = &Vt[(t & 1) * 4624 + vt_off];
        *(uint4*)dst = nv0;
        *(uint4*)(dst + 8) = nv1;
        __syncthreads();
    }

    // ---- epilogue: finish tile T-1 (possibly partial) ----
    finish(&Vt[((T - 1) & 1) * 4624], true, (T - 1) << 6);

    #pragma unroll
    for (int r = 0; r < 4; ++r) {
        const float inva = 1.0f / ola[r];
        const float invb = 1.0f / olb[r];
        const size_t rowa = bh + q0 + w * 16 + (g << 2) + r;
        const size_t rowb = rowa + 64;
        #pragma unroll
        for (int st2 = 0; st2 < 4; ++st2) {
            const float va = oa[st2][r] * inva;
            const ush ha = f2bf_rne(va);
            Qb[rowa * 64 + st2 * 16 + l15] = ha;
            ctx_lo[rowa * 64 + st2 * 16 + l15] = f2bf_rne(va - bf2f(ha));
            const float vbv = ob[st2][r] * invb;
            const ush hb = f2bf_rne(vbv);
            Qb[rowb * 64 + st2 * 16 + l15] = hb;
            ctx_lo[rowb * 64 + st2 * 16 + l15] = f2bf_rne(vbv - bf2f(hb));
        }
    }
}

// ---------------------------------------------------------------------------
// Kernel 3: out = ctx @ Wo^T + bo, 3-term split bf16 MFMA.
// 8-wave (512 threads), wave tile 64x32, 2-phase double-buffered.
// XCD-aware linear grid (same mapping as qkv) for ctx-panel L2 reuse.
// ---------------------------------------------------------------------------
__global__ __launch_bounds__(512) void out_gemm_kernel(
    const ush* __restrict__ ctx_hi, const ush* __restrict__ ctx_lo,
    const ush* __restrict__ wo_hi, const ush* __restrict__ wo_lo,
    const float* __restrict__ bo, float* __restrict__ out)
{
    __shared__ ush Ah[2][4096], Al[2][4096], Bh[2][4096], Bl[2][4096];

    const int t = threadIdx.x;
    const int w = t >> 6, l = t & 63;
    const int l15 = l & 15, g = l >> 4;

    const int j = blockIdx.x;
    const int m0 = ((j & 7) + (j >> 5) * 8) * 128;
    const int n0 = ((j >> 3) & 3) * 128;
    const int wm = (w & 1) << 6, wn = (w >> 1) << 5;

    const int srow = l >> 2;
    const int sg   = (l & 3) ^ ((srow + (srow >> 2)) & 3);
    const int fsw  = (g ^ ((l15 + (l15 >> 2)) & 3)) << 3;
    const int c0   = w;                                       // 1 chunk per wave

    f32x4 acc[4][2];
    #pragma unroll
    for (int i = 0; i < 4; ++i)
        #pragma unroll
        for (int jj = 0; jj < 2; ++jj) acc[i][jj] = (f32x4)(0.0f);

    // stage one K-tile into buffer `bf` (each wave: its chunk, 4 arrays)
    auto stage = [&](int bf, int kt) {
        const int c = c0;
        const int m = m0 + c * 16 + srow;
        const int k = kt + sg * 8;
        const size_t ga = ((size_t)((m >> 11) * 8 + (k >> 6)) * 2048 + (m & (NS - 1))) * 64 + (k & 63);
        GLL16(&ctx_hi[ga], &Ah[bf][c * 512 + l * 8]);
        GLL16(&ctx_lo[ga], &Al[bf][c * 512 + l * 8]);
        const size_t gb = (size_t)(n0 + c * 16 + srow) * 512 + kt + sg * 8;
        GLL16(&wo_hi[gb], &Bh[bf][c * 512 + l * 8]);
        GLL16(&wo_lo[gb], &Bl[bf][c * 512 + l * 8]);
    };

    stage(0, 0);
    __syncthreads();

    for (int ki = 0; ki < 16; ++ki) {
        const int buf = ki & 1;
        if (ki < 15) stage(buf ^ 1, (ki + 1) * 32);

        bf16x8 ah[4], al[4], bh4[2], bl4[2];
        #pragma unroll
        for (int mi = 0; mi < 4; ++mi) {
            const int off = (((w & 1) << 2) + mi) * 512 + l15 * 32 + fsw;
            ah[mi] = *(const bf16x8*)&Ah[buf][off];
            al[mi] = *(const bf16x8*)&Al[buf][off];
        }
        #pragma unroll
        for (int ni = 0; ni < 2; ++ni) {
            const int off = (((w >> 1) << 1) + ni) * 512 + l15 * 32 + fsw;
            bh4[ni] = *(const bf16x8*)&Bh[buf][off];
            bl4[ni] = *(const bf16x8*)&Bl[buf][off];
        }
        #pragma unroll
        for (int mi = 0; mi < 4; ++mi)
            #pragma unroll
            for (int ni = 0; ni < 2; ++ni) {
                acc[mi][ni] = __builtin_amdgcn_mfma_f32_16x16x32_bf16(ah[mi], bh4[ni], acc[mi][ni], 0, 0, 0);
                acc[mi][ni] = __builtin_amdgcn_mfma_f32_16x16x32_bf16(al[mi], bh4[ni], acc[mi][ni], 0, 0, 0);
                acc[mi][ni] = __builtin_amdgcn_mfma_f32_16x16x32_bf16(ah[mi], bl4[ni], acc[mi][ni], 0, 0, 0);
            }
        __syncthreads();   // drains this iter's GLL16s; protects buf reuse
    }

    float bov[2];
    #pragma unroll
    for (int ni = 0; ni < 2; ++ni) bov[ni] = bo[n0 + wn + ni * 16 + l15];

    #pragma unroll
    for (int mi = 0; mi < 4; ++mi)
        #pragma unroll
        for (int ni = 0; ni < 2; ++ni) {
            const int n = n0 + wn + ni * 16 + l15;
            #pragma unroll
            for (int r = 0; r < 4; ++r) {
                const int m = m0 + wm + mi * 16 + (g << 2) + r;
                out[(size_t)m * 512 + n] = acc[mi][ni][r] + bov[ni];
            }
        }
}

// ---------------------------------------------------------------------------
extern "C" void kernel_launch(void* const* d_in, const int* in_sizes, int n_in,
                              void* d_out, int out_size, void* d_ws, size_t ws_size,
                              hipStream_t stream)
{
    const float* xq   = (const float*)d_in[0];
    const float* xk   = (const float*)d_in[1];
    const float* xv   = (const float*)d_in[2];
    const float* Wq   = (const float*)d_in[3];
    const float* bq   = (const float*)d_in[4];
    const float* Wk   = (const float*)d_in[5];
    const float* bk   = (const float*)d_in[6];
    const float* Wv   = (const float*)d_in[7];
    const float* bv   = (const float*)d_in[8];
    const float* Wo   = (const float*)d_in[9];
    const float* bo   = (const float*)d_in[10];
    const int*   lens = (const int*)d_in[11];
    float* out = (float*)d_out;

    const size_t elems = (size_t)NB * NHH * NS * NDH;   // 8.39M (== B*S*D)
    ush* Qb     = (ush*)d_ws;          // bf16 Q (pre-scaled); later ctx_hi in place
    ush* Kb     = Qb + elems;
    ush* VT     = Kb + elems;          // V transposed (B,H,DH,S)
    ush* ctx_lo = VT + elems;
    ush* wbf    = ctx_lo + elems;      // Wq,Wk,Wv bf16 (3*262144)
    ush* wo_hi  = wbf + 3 * 262144;
    ush* wo_lo  = wo_hi + 262144;
    // total ws: 4*8.39M + 5*262144 shorts = 69.7 MB (< 100.7 MB proven in R1)

    // bf16 X buffers alias stream-ordered-dead regions:
    //   xq/xk -> the `out` buffer (2 x 16.78 MB = 33.5 MB = out exactly)
    //   xv    -> ctx_lo (first written by attn, after qkv has consumed xvb)
    ush* xqb = (ush*)out;
    ush* xkb = xqb + elems;
    ush* xvb = ctx_lo;

    const dim3 blk(256);
    conv_w_kernel<<<dim3(256, 4), blk, 0, stream>>>(Wq, Wk, Wv, Wo, wbf, wo_hi, wo_lo);
    conv_x_kernel<<<dim3(8192, 3), blk, 0, stream>>>(xq, xk, xv, xqb, xkb, xvb);
    qkv_gemm_kernel<<<dim3(512, 1, 3), blk, 0, stream>>>(
        xqb, xkb, xvb, wbf, bq, bk, bv, Qb, Kb, VT);
    attn_kernel<<<dim3(NB * NHH * (NS / 128)), blk, 0, stream>>>(Qb, Kb, VT, lens, ctx_lo);
    out_gemm_kernel<<<dim3(512), dim3(512), 0, stream>>>(Qb, ctx_lo, wo_hi, wo_lo, bo, out);
}